// Round 1
// baseline (56866.266 us; speedup 1.0000x reference)
//
#include <hip/hip_runtime.h>
#include <hip/hip_cooperative_groups.h>
#include <cmath>

namespace cg = cooperative_groups;

static constexpr int UNITS = 1024;
static constexpr int ORDER = 256;
static constexpr int D_IN  = 256;
static constexpr int BATCH = 64;
static constexpr int SEQ   = 512;
static constexpr int K_TOT = D_IN + UNITS + ORDER;  // 1536
static constexpr int ASTRIDE = K_TOT + 4;           // 1540: bank stagger for 4 distinct bl per wave

// ws float layout:
//   [0, BATCH*SEQ)                       XE[b*SEQ + t]  (x_t . input_encoders)
//   [BATCH*SEQ, +BATCH*ORDER)            m ping
//   [BATCH*SEQ+BATCH*ORDER, +BATCH*ORDER) m pong

__global__ __launch_bounds__(256) void lmu_pre(const float* __restrict__ x,
                                               const float* __restrict__ ie,
                                               float* __restrict__ ws) {
    int gid  = blockIdx.x * blockDim.x + threadIdx.x;
    int wave = gid >> 6;
    int lane = gid & 63;
    if (wave < BATCH * SEQ) {
        const float* row = x + (size_t)wave * D_IN;
        float s = 0.f;
        #pragma unroll
        for (int c = 0; c < D_IN; c += 64) s += row[c + lane] * ie[c + lane];
        #pragma unroll
        for (int off = 32; off > 0; off >>= 1) s += __shfl_down(s, off);
        if (lane == 0) ws[wave] = s;
    }
    // zero both m buffers
    if (gid < 2 * BATCH * ORDER) ws[BATCH * SEQ + gid] = 0.f;
}

__global__ __launch_bounds__(256, 1) void lmu_main(
        const float* __restrict__ x,
        const float* __restrict__ he,
        const float* __restrict__ me,
        const float* __restrict__ Wi,
        const float* __restrict__ Wh,
        const float* __restrict__ Wm,
        const float* __restrict__ AT,
        const float* __restrict__ BT,
        float* __restrict__ out,
        float* __restrict__ ws) {
    cg::grid_group grid = cg::this_grid();
    const int wg  = blockIdx.x;   // 256 workgroups
    const int tid = threadIdx.x;  // 256 threads

    float* XE = ws;
    float* mb0 = ws + BATCH * SEQ;
    float* mb1 = mb0 + BATCH * ORDER;

    // phase-1 role: wg -> (batch, k-chunk of 64)
    const int p1_b  = wg >> 2;
    const int p1_kc = wg & 3;
    // phase-2 role: wg -> (batch-tile of 16, unit-tile of 16)
    const int p2_b0 = (wg >> 6) * 16;
    const int p2_i  = (wg & 63) * 16 + (tid & 15);
    const int p2_bl = tid >> 4;

    __shared__ float red[256];
    __shared__ float msh[ORDER];
    extern __shared__ float act[];  // [16][ASTRIDE]

    for (int t = 0; t < SEQ; ++t) {
        float* mprev = (t & 1) ? mb1 : mb0;
        float* mnew  = (t & 1) ? mb0 : mb1;

        // ---------- phase 1: u = x.ie + h.he + m.me ; m' = m + m@AT + u*BT ----------
        {
            const int b = p1_b;
            const float* mp = mprev + b * ORDER;
            float mv = mp[tid];            // tid in [0,256) == ORDER
            msh[tid] = mv;
            float s = mv * me[tid];
            if (t > 0) {
                const float* hp = out + ((size_t)b * SEQ + (t - 1)) * UNITS;
                #pragma unroll
                for (int j = 0; j < UNITS; j += 256) s += hp[j + tid] * he[j + tid];
            }
            red[tid] = s;
            __syncthreads();               // msh + red ready
            #pragma unroll
            for (int o = 128; o > 0; o >>= 1) {
                if (tid < o) red[tid] += red[tid + o];
                __syncthreads();
            }
            const float u = XE[b * SEQ + t] + red[0];
            __syncthreads();               // everyone has read red[0]
            const int kl = tid & 63;
            const int lg = tid >> 6;
            const int k  = p1_kc * 64 + kl;
            const float* atc = AT + k;     // AT[l][k], column k
            float p = 0.f;
            for (int l = lg * 64; l < lg * 64 + 64; ++l) p += msh[l] * atc[l * ORDER];
            red[tid] = p;
            __syncthreads();
            if (lg == 0) {
                float mn = msh[k] + red[kl] + red[kl + 64] + red[kl + 128] + red[kl + 192]
                         + u * BT[k];
                mnew[b * ORDER + k] = mn;
            }
        }
        grid.sync();

        // ---------- phase 2: h' = tanh(x@Wi + h@Wh + m'@Wm) ----------
        {
            // stage [x_t | h_prev | m_new] for 16 batches into LDS
            for (int idx = tid; idx < 16 * K_TOT; idx += 256) {
                const int bl = idx / K_TOT;
                const int k  = idx - bl * K_TOT;
                const int b  = p2_b0 + bl;
                float v;
                if (k < D_IN) {
                    v = x[((size_t)b * SEQ + t) * D_IN + k];
                } else if (k < D_IN + UNITS) {
                    v = (t == 0) ? 0.f
                                 : out[((size_t)b * SEQ + (t - 1)) * UNITS + (k - D_IN)];
                } else {
                    v = mnew[b * ORDER + (k - D_IN - UNITS)];
                }
                act[bl * ASTRIDE + k] = v;
            }
            __syncthreads();

            const float* a = act + p2_bl * ASTRIDE;
            float s0 = 0.f, s1 = 0.f, s2 = 0.f, s3 = 0.f;
            {
                const float* w = Wi + p2_i;
                for (int k = 0; k < D_IN; k += 4) {
                    s0 += a[k]     * w[(k)     * UNITS];
                    s1 += a[k + 1] * w[(k + 1) * UNITS];
                    s2 += a[k + 2] * w[(k + 2) * UNITS];
                    s3 += a[k + 3] * w[(k + 3) * UNITS];
                }
            }
            {
                const float* w  = Wh + p2_i;
                const float* ah = a + D_IN;
                for (int k = 0; k < UNITS; k += 4) {
                    s0 += ah[k]     * w[(k)     * UNITS];
                    s1 += ah[k + 1] * w[(k + 1) * UNITS];
                    s2 += ah[k + 2] * w[(k + 2) * UNITS];
                    s3 += ah[k + 3] * w[(k + 3) * UNITS];
                }
            }
            {
                const float* w  = Wm + p2_i;
                const float* am = a + D_IN + UNITS;
                for (int k = 0; k < ORDER; k += 4) {
                    s0 += am[k]     * w[(k)     * UNITS];
                    s1 += am[k + 1] * w[(k + 1) * UNITS];
                    s2 += am[k + 2] * w[(k + 2) * UNITS];
                    s3 += am[k + 3] * w[(k + 3) * UNITS];
                }
            }
            const float hval = tanhf((s0 + s1) + (s2 + s3));
            out[((size_t)(p2_b0 + p2_bl) * SEQ + t) * UNITS + p2_i] = hval;
        }
        grid.sync();
    }
}

extern "C" void kernel_launch(void* const* d_in, const int* in_sizes, int n_in,
                              void* d_out, int out_size, void* d_ws, size_t ws_size,
                              hipStream_t stream) {
    const float* x  = (const float*)d_in[0];
    const float* ie = (const float*)d_in[1];
    const float* he = (const float*)d_in[2];
    const float* me = (const float*)d_in[3];
    const float* Wi = (const float*)d_in[4];
    const float* Wh = (const float*)d_in[5];
    const float* Wm = (const float*)d_in[6];
    const float* AT = (const float*)d_in[7];
    const float* BT = (const float*)d_in[8];
    float* out = (float*)d_out;
    float* ws  = (float*)d_ws;

    // XE precompute + m-buffer zeroing: one wave per (b,t) row
    hipLaunchKernelGGL(lmu_pre, dim3((BATCH * SEQ * 64) / 256), dim3(256), 0, stream,
                       x, ie, ws);

    const size_t shmem = (size_t)16 * ASTRIDE * sizeof(float);  // 98560 B
    static bool attr_set = false;
    if (!attr_set) {
        (void)hipFuncSetAttribute((const void*)lmu_main,
                                  hipFuncAttributeMaxDynamicSharedMemorySize,
                                  (int)shmem);
        attr_set = true;
    }
    void* args[] = { (void*)&x, (void*)&he, (void*)&me, (void*)&Wi, (void*)&Wh,
                     (void*)&Wm, (void*)&AT, (void*)&BT, (void*)&out, (void*)&ws };
    (void)hipLaunchCooperativeKernel((void*)lmu_main, dim3(256), dim3(256),
                                     args, (unsigned int)shmem, stream);
}

// Round 2
// 24778.183 us; speedup vs baseline: 2.2950x; 2.2950x over previous
//
#include <hip/hip_runtime.h>
#include <hip/hip_cooperative_groups.h>
#include <cmath>

namespace cg = cooperative_groups;

static constexpr int UNITS = 1024;
static constexpr int ORDER = 256;
static constexpr int D_IN  = 256;
static constexpr int BATCH = 64;
static constexpr int SEQ   = 512;
static constexpr int K_TOT = 1536;          // [x(256) | h(1024) | m(256)]
static constexpr int SROW  = K_TOT + 8;     // act row stride in bf16 elems (16B pad)

typedef __attribute__((ext_vector_type(8))) short bf16x8;
typedef __attribute__((ext_vector_type(4))) float f32x4;

// LDS byte layout
static constexpr int AHI_OFF  = 0;
static constexpr int ALO_OFF  = 16 * SROW * 2;            // 49408
static constexpr int ENC_OFF  = 2 * 16 * SROW * 2;        // 98816   he|me fp32 (1280)
static constexpr int RED_OFF  = ENC_OFF + 1280 * 4;       // 103936  3 waves x 256 f32
static constexpr int RED2_OFF = RED_OFF + 3 * 256 * 4;    // 107008
static constexpr int U_OFF    = RED2_OFF + 3 * 256 * 4;   // 110080  u[16]
static constexpr int BV_OFF   = U_OFF + 16 * 4;           // 110144  bv[16]
static constexpr int LDS_BYTES = BV_OFF + 16 * 4;         // 110208

__device__ __forceinline__ unsigned short bf16rn(float f) {
    unsigned u = __builtin_bit_cast(unsigned, f);
    u += 0x7FFFu + ((u >> 16) & 1u);
    return (unsigned short)(u >> 16);
}
__device__ __forceinline__ float bf2f(unsigned short h) {
    unsigned u = ((unsigned)h) << 16;
    return __builtin_bit_cast(float, u);
}

// ws float layout (same as round 1):
//   [0, BATCH*SEQ)        XE[b*SEQ + t]
//   [+BATCH*ORDER)        m ping
//   [+BATCH*ORDER)        m pong
__global__ __launch_bounds__(256) void lmu_pre(const float* __restrict__ x,
                                               const float* __restrict__ ie,
                                               float* __restrict__ ws) {
    int gid  = blockIdx.x * blockDim.x + threadIdx.x;
    int wave = gid >> 6;
    int lane = gid & 63;
    if (wave < BATCH * SEQ) {
        const float* row = x + (size_t)wave * D_IN;
        float s = 0.f;
        #pragma unroll
        for (int c = 0; c < D_IN; c += 64) s += row[c + lane] * ie[c + lane];
        #pragma unroll
        for (int off = 32; off > 0; off >>= 1) s += __shfl_down(s, off);
        if (lane == 0) ws[wave] = s;
    }
    if (gid < 2 * BATCH * ORDER) ws[BATCH * SEQ + gid] = 0.f;
}

__global__ __launch_bounds__(256, 1) void lmu_main(
        const float* __restrict__ x,
        const float* __restrict__ he,
        const float* __restrict__ me,
        const float* __restrict__ Wi,
        const float* __restrict__ Wh,
        const float* __restrict__ Wm,
        const float* __restrict__ AT,
        const float* __restrict__ BT,
        float* __restrict__ out,
        float* __restrict__ ws) {
    cg::grid_group grid = cg::this_grid();
    extern __shared__ char smem[];
    unsigned short* AH  = (unsigned short*)(smem + AHI_OFF);
    unsigned short* AL  = (unsigned short*)(smem + ALO_OFF);
    float* ENC  = (float*)(smem + ENC_OFF);
    float* RED  = (float*)(smem + RED_OFF);
    float* RED2 = (float*)(smem + RED2_OFF);
    float* ULDS = (float*)(smem + U_OFF);
    float* BV   = (float*)(smem + BV_OFF);

    const int wg   = blockIdx.x;    // 256
    const int tid  = threadIdx.x;   // 256
    const int wave = tid >> 6;
    const int lane = tid & 63;
    const int lrow = lane & 15;     // A-row / B-col / D-col
    const int lgrp = lane >> 4;     // k-group / D-row-group

    // wg -> (batch tile, unit tile); 4 wgs sharing a unit tile are 64 apart
    // (same wg%8 -> same XCD under round-robin) so weight L2 lines stay local.
    const int bt = wg >> 6;
    const int ut = (wg & 7) * 8 + ((wg >> 3) & 7);
    const int b0 = bt * 16;
    const int n0 = ut * 16;
    const bool is_mwg = (wg & 63) < 16;   // 16 wgs per batch tile own the m-update
    const int mt = wg & 15;

    float* XE  = ws;
    float* mb0 = ws + BATCH * SEQ;
    float* mb1 = mb0 + BATCH * ORDER;

    // ---------------- one-time setup ----------------
    for (int i = tid; i < 1280; i += 256)
        ENC[i] = (i < 1024) ? he[i] : me[i - 1024];
    {   // bv[n] = sum_l BT[l] * Wm[l][n]  for this wg's 16 units
        const int nl = tid & 15, seg = tid >> 4;
        float s = 0.f;
        for (int l = seg * 16; l < seg * 16 + 16; ++l)
            s += BT[l] * Wm[l * UNITS + n0 + nl];
        RED[tid] = s;
    }
    __syncthreads();
    if (tid < 16) {
        float s = 0.f;
        for (int seg = 0; seg < 16; ++seg) s += RED[seg * 16 + tid];
        BV[tid] = s;
    }

    // Register-resident weight fragments: W_ext = [Wi; Wh; Wm'] with
    // Wm' = (I+AT)@Wm.  B-frag: col = lane&15, k = (lane>>4)*8 + e  (same map
    // used for A-frags below -> self-consistent regardless of hw k-order).
    const int nglob = n0 + lrow;
    bf16x8 wfhi[12], wflo[12];
    #pragma unroll
    for (int j = 0; j < 12; ++j) {
        const int kbase = wave * 384 + j * 32 + lgrp * 8;
        bf16x8 vh, vl;
        #pragma unroll
        for (int e = 0; e < 8; ++e) {
            const int k = kbase + e;
            float f;
            if (k < 256) {
                f = Wi[k * UNITS + nglob];
            } else if (k < 1280) {
                f = Wh[(k - 256) * UNITS + nglob];
            } else {
                const int r = k - 1280;
                float s = Wm[r * UNITS + nglob];
                const float* atr = AT + r * ORDER;
                for (int l = 0; l < ORDER; ++l) s += atr[l] * Wm[l * UNITS + nglob];
                f = s;
            }
            unsigned short hb = bf16rn(f);
            unsigned short lb = bf16rn(f - bf2f(hb));
            vh[e] = (short)hb; vl[e] = (short)lb;
        }
        wfhi[j] = vh; wflo[j] = vl;
    }
    bf16x8 m1hi[2], m1lo[2];
    if (is_mwg) {
        #pragma unroll
        for (int j2 = 0; j2 < 2; ++j2) {
            const int kb = wave * 64 + j2 * 32 + lgrp * 8;
            const int c  = mt * 16 + lrow;
            bf16x8 vh, vl;
            #pragma unroll
            for (int e = 0; e < 8; ++e) {
                const int r = kb + e;
                float f = AT[r * ORDER + c] + ((r == c) ? 1.f : 0.f);
                unsigned short hb = bf16rn(f);
                unsigned short lb = bf16rn(f - bf2f(hb));
                vh[e] = (short)hb; vl[e] = (short)lb;
            }
            m1hi[j2] = vh; m1lo[j2] = vl;
        }
    }

    // ---------------- time loop: ONE grid.sync per step ----------------
    for (int t = 0; t < SEQ; ++t) {
        float* mprev = (t & 1) ? mb1 : mb0;
        float* mnew  = (t & 1) ? mb0 : mb1;

        // stage acts [x_t | h_{t-1} | m_{t-1}] as bf16 hi/lo planes
        #pragma unroll
        for (int bl = 0; bl < 16; ++bl) {
            const int b = b0 + bl;
            #pragma unroll
            for (int r = 0; r < 3; ++r) {
                const int k = (r * 256 + tid) * 2;   // even
                float f0, f1;
                if (k < 256) {
                    const float* p = x + ((size_t)b * SEQ + t) * D_IN + k;
                    f0 = p[0]; f1 = p[1];
                } else if (k < 1280) {
                    if (t == 0) { f0 = 0.f; f1 = 0.f; }
                    else {
                        const float* p = out + ((size_t)b * SEQ + (t - 1)) * UNITS + (k - 256);
                        f0 = p[0]; f1 = p[1];
                    }
                } else {
                    const float* p = mprev + b * ORDER + (k - 1280);
                    f0 = p[0]; f1 = p[1];
                }
                unsigned short h0 = bf16rn(f0), h1 = bf16rn(f1);
                unsigned short l0 = bf16rn(f0 - bf2f(h0)), l1 = bf16rn(f1 - bf2f(h1));
                *(unsigned*)&AH[bl * SROW + k] = (unsigned)h0 | ((unsigned)h1 << 16);
                *(unsigned*)&AL[bl * SROW + k] = (unsigned)l0 | ((unsigned)l1 << 16);
            }
        }
        __syncthreads();

        // u[b] = XE + h.he + m.me  (reconstruct fp32 = hi+lo from LDS)
        {
            const int bl = tid >> 4, part = tid & 15;
            float s = 0.f;
            const int kstart = 256 + part * 80;
            for (int q = 0; q < 80; q += 2) {
                const int k = kstart + q;
                unsigned wh = *(const unsigned*)&AH[bl * SROW + k];
                unsigned wl = *(const unsigned*)&AL[bl * SROW + k];
                float v0 = bf2f((unsigned short)(wh & 0xFFFFu)) + bf2f((unsigned short)(wl & 0xFFFFu));
                float v1 = bf2f((unsigned short)(wh >> 16)) + bf2f((unsigned short)(wl >> 16));
                s += v0 * ENC[k - 256] + v1 * ENC[k - 255];
            }
            #pragma unroll
            for (int o = 1; o < 16; o <<= 1) s += __shfl_xor(s, o, 64);
            if (part == 0) ULDS[bl] = XE[(size_t)(b0 + bl) * SEQ + t] + s;
        }

        // h-tile MFMA: K split 4 ways across waves, 3-term bf16 split
        f32x4 acc = {0.f, 0.f, 0.f, 0.f};
        #pragma unroll
        for (int j = 0; j < 12; ++j) {
            const int kof = wave * 384 + j * 32 + lgrp * 8;
            bf16x8 ah = *(const bf16x8*)&AH[lrow * SROW + kof];
            bf16x8 al = *(const bf16x8*)&AL[lrow * SROW + kof];
            acc = __builtin_amdgcn_mfma_f32_16x16x32_bf16(ah, wfhi[j], acc, 0, 0, 0);
            acc = __builtin_amdgcn_mfma_f32_16x16x32_bf16(ah, wflo[j], acc, 0, 0, 0);
            acc = __builtin_amdgcn_mfma_f32_16x16x32_bf16(al, wfhi[j], acc, 0, 0, 0);
        }
        // m-tile MFMA (m_t = m_{t-1}@(I+AT) + u*BT), only on 64 wgs
        f32x4 acc2 = {0.f, 0.f, 0.f, 0.f};
        if (is_mwg) {
            #pragma unroll
            for (int j2 = 0; j2 < 2; ++j2) {
                const int kof = 1280 + wave * 64 + j2 * 32 + lgrp * 8;
                bf16x8 ah = *(const bf16x8*)&AH[lrow * SROW + kof];
                bf16x8 al = *(const bf16x8*)&AL[lrow * SROW + kof];
                acc2 = __builtin_amdgcn_mfma_f32_16x16x32_bf16(ah, m1hi[j2], acc2, 0, 0, 0);
                acc2 = __builtin_amdgcn_mfma_f32_16x16x32_bf16(ah, m1lo[j2], acc2, 0, 0, 0);
                acc2 = __builtin_amdgcn_mfma_f32_16x16x32_bf16(al, m1hi[j2], acc2, 0, 0, 0);
            }
        }
        if (wave != 0) {
            ((f32x4*)RED)[(wave - 1) * 64 + lane] = acc;
            if (is_mwg) ((f32x4*)RED2)[(wave - 1) * 64 + lane] = acc2;
        }
        __syncthreads();

        if (wave == 0) {
            f32x4 a0 = acc;
            #pragma unroll
            for (int w = 0; w < 3; ++w) a0 += ((const f32x4*)RED)[w * 64 + lane];
            const float bvn = BV[lrow];
            #pragma unroll
            for (int r = 0; r < 4; ++r) {
                const int brow = lgrp * 4 + r;
                float v = a0[r] + ULDS[brow] * bvn;
                out[((size_t)(b0 + brow) * SEQ + t) * UNITS + n0 + lrow] = tanhf(v);
            }
            if (is_mwg) {
                f32x4 a2 = acc2;
                #pragma unroll
                for (int w = 0; w < 3; ++w) a2 += ((const f32x4*)RED2)[w * 64 + lane];
                const float btc = BT[mt * 16 + lrow];
                #pragma unroll
                for (int r = 0; r < 4; ++r) {
                    const int brow = lgrp * 4 + r;
                    mnew[(b0 + brow) * ORDER + mt * 16 + lrow] = a2[r] + ULDS[brow] * btc;
                }
            }
        }
        grid.sync();
    }
}

extern "C" void kernel_launch(void* const* d_in, const int* in_sizes, int n_in,
                              void* d_out, int out_size, void* d_ws, size_t ws_size,
                              hipStream_t stream) {
    const float* x  = (const float*)d_in[0];
    const float* ie = (const float*)d_in[1];
    const float* he = (const float*)d_in[2];
    const float* me = (const float*)d_in[3];
    const float* Wi = (const float*)d_in[4];
    const float* Wh = (const float*)d_in[5];
    const float* Wm = (const float*)d_in[6];
    const float* AT = (const float*)d_in[7];
    const float* BT = (const float*)d_in[8];
    float* out = (float*)d_out;
    float* ws  = (float*)d_ws;

    hipLaunchKernelGGL(lmu_pre, dim3((BATCH * SEQ * 64) / 256), dim3(256), 0, stream,
                       x, ie, ws);

    static bool attr_set = false;
    if (!attr_set) {
        (void)hipFuncSetAttribute((const void*)lmu_main,
                                  hipFuncAttributeMaxDynamicSharedMemorySize,
                                  LDS_BYTES);
        attr_set = true;
    }
    void* args[] = { (void*)&x, (void*)&he, (void*)&me, (void*)&Wi, (void*)&Wh,
                     (void*)&Wm, (void*)&AT, (void*)&BT, (void*)&out, (void*)&ws };
    (void)hipLaunchCooperativeKernel((void*)lmu_main, dim3(256), dim3(256),
                                     args, (unsigned int)LDS_BYTES, stream);
}

// Round 3
// 15311.769 us; speedup vs baseline: 3.7139x; 1.6182x over previous
//
#include <hip/hip_runtime.h>
#include <cmath>

static constexpr int UNITS = 1024;
static constexpr int ORDER = 256;
static constexpr int D_IN  = 256;
static constexpr int BATCH = 64;
static constexpr int SEQ   = 512;
static constexpr int ROWB  = 3072;   // plane row bytes (1536 bf16)

// ws byte layout
static constexpr size_t XE_OFF = 0;          // 64*512 f32 = 131072
static constexpr size_t FG_OFF = 131072;     // 4 groups * 256 u32 = 4096
static constexpr size_t UW_OFF = 135168;     // 64 f32 = 256 (+pad)
static constexpr size_t P_OFF  = 136192;     // planeset s: hi @ +s*393216, lo @ +196608
static constexpr size_t PSET   = 393216;     // end = 136192 + 786432 = 922624 B

typedef __attribute__((ext_vector_type(8))) short bf16x8;
typedef __attribute__((ext_vector_type(4))) float f32x4;

// LDS byte layout (dynamic)
static constexpr int AH_OFF   = 0;           // 16 rows * 3072
static constexpr int AL_OFF   = 49152;       // 16 rows * 3072
static constexpr int RED_OFF  = 98304;       // 3072 (3 waves * 64 * f32x4)
static constexpr int RED2_OFF = 101376;      // 3072
static constexpr int BV_OFF   = 104448;      // 64
static constexpr int LDS_BYTES = 104512;

__device__ __forceinline__ unsigned short bf16rn(float f) {
    unsigned u = __builtin_bit_cast(unsigned, f);
    u += 0x7FFFu + ((u >> 16) & 1u);
    return (unsigned short)(u >> 16);
}
__device__ __forceinline__ float bf2f(unsigned short h) {
    unsigned u = ((unsigned)h) << 16;
    return __builtin_bit_cast(float, u);
}

__device__ __forceinline__ void gl_lds16(const char* g, char* l) {
    __builtin_amdgcn_global_load_lds(
        (const __attribute__((address_space(1))) void*)g,
        (__attribute__((address_space(3))) void*)l, 16, 0, 0);
}

// 64-wg group barrier: release own flag, wave0 polls all 64, acquire, syncthreads.
__device__ __forceinline__ void gbar(unsigned* gf, int lid, unsigned gen) {
    __syncthreads();
    if (threadIdx.x == 0)
        __hip_atomic_store(&gf[lid], gen, __ATOMIC_RELEASE, __HIP_MEMORY_SCOPE_AGENT);
    if (threadIdx.x < 64) {
        while (__hip_atomic_load(&gf[threadIdx.x], __ATOMIC_RELAXED,
                                 __HIP_MEMORY_SCOPE_AGENT) < gen)
            __builtin_amdgcn_s_sleep(1);
    }
    __builtin_amdgcn_fence(__ATOMIC_ACQUIRE, "agent");
    __syncthreads();
}

__global__ __launch_bounds__(256) void lmu_pre(const float* __restrict__ x,
                                               const float* __restrict__ ie,
                                               char* __restrict__ ws) {
    int gid  = blockIdx.x * blockDim.x + threadIdx.x;
    int wave = gid >> 6;
    int lane = gid & 63;
    if (wave < BATCH * SEQ) {
        const float* row = x + (size_t)wave * D_IN;
        float s = 0.f;
        #pragma unroll
        for (int c = 0; c < D_IN; c += 64) s += row[c + lane] * ie[c + lane];
        #pragma unroll
        for (int off = 32; off > 0; off >>= 1) s += __shfl_down(s, off);
        if (lane == 0) ((float*)(ws + XE_OFF))[wave] = s;
    }
    if (gid < 1024) ((unsigned*)(ws + FG_OFF))[gid] = 0u;
}

__global__ __launch_bounds__(256, 1) void lmu_main(
        const float* __restrict__ x,
        const float* __restrict__ he,
        const float* __restrict__ me,
        const float* __restrict__ Wi,
        const float* __restrict__ Wh,
        const float* __restrict__ Wm,
        const float* __restrict__ AT,
        const float* __restrict__ BT,
        float* __restrict__ out,
        char* __restrict__ ws) {
    extern __shared__ char smem[];
    float* RED  = (float*)(smem + RED_OFF);
    float* RED2 = (float*)(smem + RED2_OFF);
    float* BV   = (float*)(smem + BV_OFF);
    float* WMC  = (float*)(smem + AH_OFF);   // setup-only alias (16 KB)

    const int wg = blockIdx.x, tid = threadIdx.x;
    const int wave = tid >> 6, lane = tid & 63;
    const int lrow = lane & 15, lgrp = lane >> 4;
    const int grp = wg >> 6, lid = wg & 63;
    const int b0 = grp * 16, n0 = lid * 16, nglob = n0 + lrow;
    const bool stager = (lid < 16);
    const int bb = b0 + lid;        // valid when stager
    const bool mwg = stager;        // same 16 wgs own the m-tile
    const int mt = lid;

    float* XE = (float*)(ws + XE_OFF);
    unsigned* gf = (unsigned*)(ws + FG_OFF) + (size_t)grp * 256;
    float* UW = (float*)(ws + UW_OFF);

    // ---------------- setup ----------------
    // Wm columns for this wg's 16 units -> LDS
    for (int idx = tid; idx < ORDER * 16; idx += 256)
        WMC[idx] = Wm[(size_t)(idx >> 4) * UNITS + n0 + (idx & 15)];
    __syncthreads();

    // weight fragments: [Wi; Wh; Wm'] with Wm' = (I+AT)@Wm, bf16 hi/lo
    bf16x8 wfhi[12], wflo[12];
    #pragma unroll
    for (int j = 0; j < 12; ++j) {
        const int kbase = wave * 384 + j * 32 + lgrp * 8;
        bf16x8 vh, vl;
        #pragma unroll
        for (int e = 0; e < 8; ++e) {
            const int k = kbase + e;
            float f;
            if (k < 256)       f = Wi[(size_t)k * UNITS + nglob];
            else if (k < 1280) f = Wh[(size_t)(k - 256) * UNITS + nglob];
            else {
                const int r = k - 1280;
                float s = WMC[r * 16 + lrow];
                const float* atr = AT + (size_t)r * ORDER;
                for (int l = 0; l < ORDER; ++l) s += atr[l] * WMC[l * 16 + lrow];
                f = s;
            }
            unsigned short hb = bf16rn(f);
            unsigned short lb = bf16rn(f - bf2f(hb));
            vh[e] = (short)hb; vl[e] = (short)lb;
        }
        wfhi[j] = vh; wflo[j] = vl;
    }
    // bv[n] = sum_l BT[l] * Wm[l][n]
    {
        const int nl = tid & 15, seg = tid >> 4;
        float s = 0.f;
        for (int l = seg * 16; l < seg * 16 + 16; ++l) s += BT[l] * WMC[l * 16 + nl];
        RED[tid] = s;
    }
    __syncthreads();
    if (tid < 16) {
        float s = 0.f;
        for (int sg = 0; sg < 16; ++sg) s += RED[sg * 16 + tid];
        BV[tid] = s;
    }
    // M1 = (I+AT) fragments for the m-tile wgs
    bf16x8 m1hi[2], m1lo[2];
    float btreg = 0.f;
    if (mwg) {
        #pragma unroll
        for (int j2 = 0; j2 < 2; ++j2) {
            const int kb = wave * 64 + j2 * 32 + lgrp * 8;
            const int c = mt * 16 + lrow;
            bf16x8 vh, vl;
            #pragma unroll
            for (int e = 0; e < 8; ++e) {
                const int r = kb + e;
                float f = AT[(size_t)r * ORDER + c] + ((r == c) ? 1.f : 0.f);
                unsigned short hb = bf16rn(f);
                unsigned short lb = bf16rn(f - bf2f(hb));
                vh[e] = (short)hb; vl[e] = (short)lb;
            }
            m1hi[j2] = vh; m1lo[j2] = vl;
        }
        btreg = BT[mt * 16 + lrow];
    }
    __syncthreads();   // WMC (aliases AH) dead from here

    // ---------------- time loop: 2 group-barriers per step ----------------
    for (int t = 0; t < SEQ; ++t) {
        char* PHc = ws + P_OFF + (size_t)(t & 1) * PSET;       // set read at step t
        char* PLc = PHc + 196608;
        char* PHn = ws + P_OFF + (size_t)((t + 1) & 1) * PSET; // m_t goes here
        char* PLn = PHn + 196608;

        gbar(gf, lid, (unsigned)(2 * t + 1));

        // ---- phase A: stagers compute u and write x/h (and t=0 m) planes ----
        if (stager) {
            char* rh = PHc + (size_t)bb * ROWB;
            char* rl = PLc + (size_t)bb * ROWB;
            const unsigned swz = ((unsigned)(bb & 7)) << 4;
            float2 ha = {0.f, 0.f}, hb2 = {0.f, 0.f};
            float s = 0.f;
            if (t > 0) {
                const float2* hp2 = (const float2*)(out + ((size_t)bb * SEQ + (t - 1)) * UNITS);
                const float2* he2 = (const float2*)he;
                ha = hp2[tid]; hb2 = hp2[256 + tid];
                float2 ea = he2[tid], eb = he2[256 + tid];
                s = ha.x * ea.x + ha.y * ea.y + hb2.x * eb.x + hb2.y * eb.y;
            }
            if (tid < 128) {
                float m0 = 0.f, m1 = 0.f;
                if (t > 0) {
                    const unsigned k2 = (unsigned)(1280 + 2 * tid) * 2;
                    unsigned mh = *(const unsigned*)(rh + (k2 ^ swz));
                    unsigned ml = *(const unsigned*)(rl + (k2 ^ swz));
                    m0 = bf2f((unsigned short)(mh & 0xffffu)) + bf2f((unsigned short)(ml & 0xffffu));
                    m1 = bf2f((unsigned short)(mh >> 16)) + bf2f((unsigned short)(ml >> 16));
                }
                const float2 me2 = ((const float2*)me)[tid];
                s += m0 * me2.x + m1 * me2.y;
            }
            RED[tid] = s;
            __syncthreads();
            #pragma unroll
            for (int o = 128; o > 0; o >>= 1) {
                if (tid < o) RED[tid] += RED[tid + o];
                __syncthreads();
            }
            if (tid == 0) UW[bb] = XE[(size_t)bb * SEQ + t] + RED[0];
            // h plane pairs (zeros at t=0)
            {
                unsigned h0 = bf16rn(ha.x), h1 = bf16rn(ha.y);
                unsigned l0 = bf16rn(ha.x - bf2f((unsigned short)h0));
                unsigned l1 = bf16rn(ha.y - bf2f((unsigned short)h1));
                unsigned k2 = (unsigned)(256 + 2 * tid) * 2;
                *(unsigned*)(rh + (k2 ^ swz)) = h0 | (h1 << 16);
                *(unsigned*)(rl + (k2 ^ swz)) = l0 | (l1 << 16);
                h0 = bf16rn(hb2.x); h1 = bf16rn(hb2.y);
                l0 = bf16rn(hb2.x - bf2f((unsigned short)h0));
                l1 = bf16rn(hb2.y - bf2f((unsigned short)h1));
                k2 = (unsigned)(768 + 2 * tid) * 2;
                *(unsigned*)(rh + (k2 ^ swz)) = h0 | (h1 << 16);
                *(unsigned*)(rl + (k2 ^ swz)) = l0 | (l1 << 16);
            }
            if (tid < 128) {
                float2 xv = ((const float2*)(x + ((size_t)bb * SEQ + t) * D_IN))[tid];
                unsigned h0 = bf16rn(xv.x), h1 = bf16rn(xv.y);
                unsigned l0 = bf16rn(xv.x - bf2f((unsigned short)h0));
                unsigned l1 = bf16rn(xv.y - bf2f((unsigned short)h1));
                unsigned k2 = (unsigned)(2 * tid) * 2;
                *(unsigned*)(rh + (k2 ^ swz)) = h0 | (h1 << 16);
                *(unsigned*)(rl + (k2 ^ swz)) = l0 | (l1 << 16);
                if (t == 0) {
                    k2 = (unsigned)(1280 + 2 * tid) * 2;
                    *(unsigned*)(rh + (k2 ^ swz)) = 0u;
                    *(unsigned*)(rl + (k2 ^ swz)) = 0u;
                }
            }
        }

        gbar(gf, lid, (unsigned)(2 * t + 2));

        // ---- phase B: stage planes -> LDS via global_load_lds ----
        #pragma unroll
        for (int r2 = 0; r2 < 4; ++r2) {
            const int r = wave * 4 + r2;
            const size_t rowg = (size_t)(b0 + r) * ROWB;
            char* ldh = smem + AH_OFF + r * ROWB;
            char* ldl = smem + AL_OFF + r * ROWB;
            #pragma unroll
            for (int c = 0; c < 3; ++c) {
                gl_lds16(PHc + rowg + (size_t)c * 1024 + (size_t)lane * 16, ldh + c * 1024);
                gl_lds16(PLc + rowg + (size_t)c * 1024 + (size_t)lane * 16, ldl + c * 1024);
            }
        }
        __syncthreads();

        // ---- MFMA: h-tile (K split over 4 waves, 3-term bf16) ----
        f32x4 acc = {0.f, 0.f, 0.f, 0.f};
        const char* arh = smem + AH_OFF + lrow * ROWB;
        const char* arl = smem + AL_OFF + lrow * ROWB;
        const unsigned swzr = ((unsigned)(lrow & 7)) << 4;
        #pragma unroll
        for (int j = 0; j < 12; ++j) {
            const unsigned boff = ((unsigned)((wave * 384 + j * 32 + lgrp * 8) * 2)) ^ swzr;
            bf16x8 ah = *(const bf16x8*)(arh + boff);
            bf16x8 al = *(const bf16x8*)(arl + boff);
            acc = __builtin_amdgcn_mfma_f32_16x16x32_bf16(ah, wfhi[j], acc, 0, 0, 0);
            acc = __builtin_amdgcn_mfma_f32_16x16x32_bf16(ah, wflo[j], acc, 0, 0, 0);
            acc = __builtin_amdgcn_mfma_f32_16x16x32_bf16(al, wfhi[j], acc, 0, 0, 0);
        }
        // ---- m-tile MFMA (mwgs): m_t = m_{t-1}@(I+AT) + u*BT ----
        f32x4 acc2 = {0.f, 0.f, 0.f, 0.f};
        if (mwg) {
            #pragma unroll
            for (int j2 = 0; j2 < 2; ++j2) {
                const unsigned kof = (unsigned)(1280 + wave * 64 + j2 * 32 + lgrp * 8);
                const unsigned boff = (kof * 2) ^ swzr;
                bf16x8 ah = *(const bf16x8*)(arh + boff);
                bf16x8 al = *(const bf16x8*)(arl + boff);
                acc2 = __builtin_amdgcn_mfma_f32_16x16x32_bf16(ah, m1hi[j2], acc2, 0, 0, 0);
                acc2 = __builtin_amdgcn_mfma_f32_16x16x32_bf16(ah, m1lo[j2], acc2, 0, 0, 0);
                acc2 = __builtin_amdgcn_mfma_f32_16x16x32_bf16(al, m1hi[j2], acc2, 0, 0, 0);
            }
        }
        if (wave != 0) {
            ((f32x4*)RED)[(wave - 1) * 64 + lane] = acc;
            if (mwg) ((f32x4*)RED2)[(wave - 1) * 64 + lane] = acc2;
        }
        __syncthreads();

        if (wave == 0) {
            f32x4 a0 = acc;
            #pragma unroll
            for (int w = 0; w < 3; ++w) a0 += ((const f32x4*)RED)[w * 64 + lane];
            const float bvn = BV[lrow];
            #pragma unroll
            for (int r = 0; r < 4; ++r) {
                const int brow = lgrp * 4 + r;
                const float uu = UW[b0 + brow];
                out[((size_t)(b0 + brow) * SEQ + t) * UNITS + n0 + lrow] =
                    tanhf(a0[r] + uu * bvn);
            }
            if (mwg) {
                f32x4 a2 = acc2;
                #pragma unroll
                for (int w = 0; w < 3; ++w) a2 += ((const f32x4*)RED2)[w * 64 + lane];
                const int c = mt * 16 + lrow;
                #pragma unroll
                for (int r = 0; r < 4; ++r) {
                    const int brow = lgrp * 4 + r;
                    const float mval = a2[r] + UW[b0 + brow] * btreg;
                    const unsigned k2 = (unsigned)(1280 + c) * 2;
                    const unsigned swz2 = ((unsigned)((b0 + brow) & 7)) << 4;
                    unsigned short mh = bf16rn(mval);
                    unsigned short mlw = bf16rn(mval - bf2f(mh));
                    *(unsigned short*)(PHn + (size_t)(b0 + brow) * ROWB + (k2 ^ swz2)) = mh;
                    *(unsigned short*)(PLn + (size_t)(b0 + brow) * ROWB + (k2 ^ swz2)) = mlw;
                }
            }
        }
    }
}

extern "C" void kernel_launch(void* const* d_in, const int* in_sizes, int n_in,
                              void* d_out, int out_size, void* d_ws, size_t ws_size,
                              hipStream_t stream) {
    const float* x  = (const float*)d_in[0];
    const float* ie = (const float*)d_in[1];
    const float* he = (const float*)d_in[2];
    const float* me = (const float*)d_in[3];
    const float* Wi = (const float*)d_in[4];
    const float* Wh = (const float*)d_in[5];
    const float* Wm = (const float*)d_in[6];
    const float* AT = (const float*)d_in[7];
    const float* BT = (const float*)d_in[8];
    float* out = (float*)d_out;
    char* ws   = (char*)d_ws;

    hipLaunchKernelGGL(lmu_pre, dim3((BATCH * SEQ * 64) / 256), dim3(256), 0, stream,
                       x, ie, ws);

    static bool attr_set = false;
    if (!attr_set) {
        (void)hipFuncSetAttribute((const void*)lmu_main,
                                  hipFuncAttributeMaxDynamicSharedMemorySize,
                                  LDS_BYTES);
        attr_set = true;
    }
    void* args[] = { (void*)&x, (void*)&he, (void*)&me, (void*)&Wi, (void*)&Wh,
                     (void*)&Wm, (void*)&AT, (void*)&BT, (void*)&out, (void*)&ws };
    (void)hipLaunchCooperativeKernel((void*)lmu_main, dim3(256), dim3(256),
                                     args, (unsigned int)LDS_BYTES, stream);
}

// Round 8
// 8904.301 us; speedup vs baseline: 6.3864x; 1.7196x over previous
//
#include <hip/hip_runtime.h>
#include <cmath>

static constexpr int UNITS = 1024;
static constexpr int ORDER = 256;
static constexpr int D_IN  = 256;
static constexpr int BATCH = 64;
static constexpr int SEQ   = 512;
static constexpr int PROWB = 2560;          // plane row bytes: (h 1024 + m 256) * 2B

// ws byte layout
static constexpr size_t XE_OFF = 0;         // 64*512 f32 = 131072
static constexpr size_t FG_OFF = 131072;    // 4 groups * 256 u32 = 4096
static constexpr size_t UP_OFF = 135168;    // 2 slots * 64 b * 80 f32 = 40960
static constexpr size_t P_OFF  = 176128;    // 2 sets * PSET
static constexpr size_t PSET   = 327680;    // 64 rows * 2560 B * 2 (hi,lo)
static constexpr size_t PLO    = 163840;    // lo-plane offset within a set
// contiguous zero region [FG_OFF, P_OFF+2*PSET) = 700416 B = 175104 words

// dynamic-LDS byte offsets (base is 16B-aligned; all offsets 16B multiples)
static constexpr int SXH_OFF  = 0;          // x hi plane  [16][528B]
static constexpr int SXL_OFF  = 8448;       // x lo plane  [16][528B]
static constexpr int RED_OFF  = 16896;      // 3 waves * 64 lanes * f32x4 = 3072 B
static constexpr int RED2_OFF = 19968;      // 3072 B
static constexpr int ULDS_OFF = 23040;      // 16 f32
static constexpr int BVS_OFF  = 23104;      // 16 f32
static constexpr int LDS_BYTES = 23168;
// setup-only alias: WMC = [256][16] f32 = 16384 B at offset 0 (< 16896)

typedef __attribute__((ext_vector_type(8))) short bf16x8;
typedef __attribute__((ext_vector_type(4))) float f32x4;

__device__ __forceinline__ unsigned short bf16rn(float f) {
    unsigned u = __builtin_bit_cast(unsigned, f);
    u += 0x7FFFu + ((u >> 16) & 1u);
    return (unsigned short)(u >> 16);
}
__device__ __forceinline__ float bf2f(unsigned short h) {
    unsigned u = ((unsigned)h) << 16;
    return __builtin_bit_cast(float, u);
}

// 64-wg group barrier: release own flag, threads 0-63 poll, acquire, syncthreads.
// Safe without cooperative launch: 256 blocks x (23KB LDS, 4 waves) on 256 CUs
// => capacity >= 2 blocks/CU * 256 CUs = 512 slots > 256 blocks, so ALL blocks
// are resident no matter how the dispatcher places them; the spin cannot starve.
__device__ __forceinline__ void gbar(unsigned* gf, int lid, unsigned gen) {
    __syncthreads();
    if (threadIdx.x == 0)
        __hip_atomic_store(&gf[lid], gen, __ATOMIC_RELEASE, __HIP_MEMORY_SCOPE_AGENT);
    if (threadIdx.x < 64) {
        while (__hip_atomic_load(&gf[threadIdx.x], __ATOMIC_RELAXED,
                                 __HIP_MEMORY_SCOPE_AGENT) < gen)
            __builtin_amdgcn_s_sleep(1);
    }
    __builtin_amdgcn_fence(__ATOMIC_ACQUIRE, "agent");
    __syncthreads();
}

__global__ __launch_bounds__(256) void lmu_pre(const float* __restrict__ x,
                                               const float* __restrict__ ie,
                                               char* __restrict__ ws) {
    int gid  = blockIdx.x * blockDim.x + threadIdx.x;
    int wave = gid >> 6;
    int lane = gid & 63;
    if (wave < BATCH * SEQ) {
        const float* row = x + (size_t)wave * D_IN;
        float s = 0.f;
        #pragma unroll
        for (int c = 0; c < D_IN; c += 64) s += row[c + lane] * ie[c + lane];
        #pragma unroll
        for (int off = 32; off > 0; off >>= 1) s += __shfl_down(s, off);
        if (lane == 0) ((float*)(ws + XE_OFF))[wave] = s;
    }
    // zero flags + both UP slots + both plane sets (contiguous region)
    if (gid < 175104) ((unsigned*)(ws + FG_OFF))[gid] = 0u;
}

__global__ __launch_bounds__(256, 1) void lmu_main(
        const float* __restrict__ x,
        const float* __restrict__ he,
        const float* __restrict__ me,
        const float* __restrict__ Wi,
        const float* __restrict__ Wh,
        const float* __restrict__ Wm,
        const float* __restrict__ AT,
        const float* __restrict__ BT,
        float* __restrict__ out,
        char* __restrict__ ws) {
    extern __shared__ char smem[];
    char*  sXH  = smem + SXH_OFF;
    char*  sXL  = smem + SXL_OFF;
    float* RED  = (float*)(smem + RED_OFF);
    float* RED2 = (float*)(smem + RED2_OFF);
    float* ULDS = (float*)(smem + ULDS_OFF);
    float* BVs  = (float*)(smem + BVS_OFF);
    float* WMC  = (float*)smem;              // setup-only alias

    const int wg = blockIdx.x, tid = threadIdx.x;
    const int wave = tid >> 6, lane = tid & 63;
    const int lrow = lane & 15, lgrp = lane >> 4;
    const int grp = wg >> 6, lid = wg & 63;
    const int b0 = grp * 16, n0 = lid * 16, nglob = n0 + lrow;
    const bool mwg = (lid < 16);
    const int mt = lid & 15;

    float* XE  = (float*)(ws + XE_OFF);
    unsigned* gf = (unsigned*)(ws + FG_OFF) + (size_t)grp * 256;
    float* UPf = (float*)(ws + UP_OFF);
    char* PB   = ws + P_OFF;

    // ---------------- setup ----------------
    for (int idx = tid; idx < ORDER * 16; idx += 256)
        WMC[idx] = Wm[(size_t)(idx >> 4) * UNITS + n0 + (idx & 15)];
    __syncthreads();

    // weight fragments: [Wi; Wh; Wm'] with Wm' = (I+AT)@Wm, 2-plane bf16
    bf16x8 wfhi[12], wflo[12];
    #pragma unroll
    for (int j = 0; j < 12; ++j) {
        const int kbase = wave * 384 + j * 32 + lgrp * 8;
        bf16x8 vh, vl;
        #pragma unroll
        for (int e = 0; e < 8; ++e) {
            const int k = kbase + e;
            float f;
            if (k < 256)       f = Wi[(size_t)k * UNITS + nglob];
            else if (k < 1280) f = Wh[(size_t)(k - 256) * UNITS + nglob];
            else {
                const int r = k - 1280;
                float s = WMC[r * 16 + lrow];
                const float* atr = AT + (size_t)r * ORDER;
                for (int l = 0; l < ORDER; ++l) s += atr[l] * WMC[l * 16 + lrow];
                f = s;
            }
            unsigned short hb = bf16rn(f);
            unsigned short lb = bf16rn(f - bf2f(hb));
            vh[e] = (short)hb; vl[e] = (short)lb;
        }
        wfhi[j] = vh; wflo[j] = vl;
    }
    // bv[n] = sum_l BT[l] * Wm[l][n]
    {
        const int nl = tid & 15, seg = tid >> 4;
        float s = 0.f;
        for (int l = seg * 16; l < seg * 16 + 16; ++l) s += BT[l] * WMC[l * 16 + nl];
        RED[tid] = s;
    }
    __syncthreads();               // also: all WMC reads done
    if (tid < 16) {
        float s = 0.f;
        for (int sg = 0; sg < 16; ++sg) s += RED[sg * 16 + tid];
        BVs[tid] = s;
    }
    // M1 = (I+AT) fragments for owner wgs
    bf16x8 m1hi[2], m1lo[2];
    float btreg = 0.f, mereg = 0.f;
    if (mwg) {
        #pragma unroll
        for (int j2 = 0; j2 < 2; ++j2) {
            const int kb = wave * 64 + j2 * 32 + lgrp * 8;
            const int c = mt * 16 + lrow;
            bf16x8 vh, vl;
            #pragma unroll
            for (int e = 0; e < 8; ++e) {
                const int r = kb + e;
                float f = AT[(size_t)r * ORDER + c] + ((r == c) ? 1.f : 0.f);
                unsigned short hb = bf16rn(f);
                unsigned short lb = bf16rn(f - bf2f(hb));
                vh[e] = (short)hb; vl[e] = (short)lb;
            }
            m1hi[j2] = vh; m1lo[j2] = vl;
        }
        btreg = BT[mt * 16 + lrow];
        mereg = me[mt * 16 + lrow];
    }
    __syncthreads();
    const float bvreg = BVs[lrow];
    const float hereg = he[n0 + lrow];

    // ---------------- time loop: ONE group barrier per step ----------------
    for (int t = 0; t < SEQ; ++t) {
        // stage x_t (wg-local, pre-barrier): fp32 -> bf16 hi/lo into sX
        {
            const int row = tid >> 4, cs = tid & 15;
            const float4* xr = (const float4*)(x + ((size_t)(b0 + row) * SEQ + t) * D_IN
                                               + cs * 16);
            float4 v0 = xr[0], v1 = xr[1], v2 = xr[2], v3 = xr[3];
            float fs[16] = {v0.x,v0.y,v0.z,v0.w, v1.x,v1.y,v1.z,v1.w,
                            v2.x,v2.y,v2.z,v2.w, v3.x,v3.y,v3.z,v3.w};
            unsigned* dh = (unsigned*)(sXH + row * 528 + cs * 32);
            unsigned* dl = (unsigned*)(sXL + row * 528 + cs * 32);
            #pragma unroll
            for (int q = 0; q < 8; ++q) {
                unsigned short h0 = bf16rn(fs[2*q]),   h1 = bf16rn(fs[2*q+1]);
                unsigned short l0 = bf16rn(fs[2*q]   - bf2f(h0));
                unsigned short l1 = bf16rn(fs[2*q+1] - bf2f(h1));
                dh[q] = (unsigned)h0 | ((unsigned)h1 << 16);
                dl[q] = (unsigned)l0 | ((unsigned)l1 << 16);
            }
        }

        gbar(gf, lid, (unsigned)(t + 1));

        const char* PHc = PB + (size_t)(t & 1) * PSET;
        const char* PLc = PHc + PLO;
        const char* phr = PHc + (size_t)(b0 + lrow) * PROWB;
        const char* plr = PLc + (size_t)(b0 + lrow) * PROWB;

        // u reduction (wave0): u[b] = XE + sum of 80 partials
        if (wave == 0) {
            const int bl = lane >> 2, q = lane & 3;
            const float* pp = UPf + ((size_t)(t & 1) * 64 + b0 + bl) * 80 + q * 20;
            float s = 0.f;
            #pragma unroll
            for (int i = 0; i < 5; ++i) {
                float4 v = ((const float4*)pp)[i];
                s += (v.x + v.y) + (v.z + v.w);
            }
            s += __shfl_xor(s, 1, 64);
            s += __shfl_xor(s, 2, 64);
            if (q == 0) ULDS[bl] = XE[(size_t)(b0 + bl) * SEQ + t] + s;
        }

        // h-tile MFMA: A = [x(LDS) | h,m (global planes)] vs register weights
        f32x4 acc = {0.f, 0.f, 0.f, 0.f};
        #pragma unroll
        for (int j = 0; j < 12; ++j) {
            const int kbase = wave * 384 + j * 32;
            bf16x8 ah, al;
            if (kbase < 256) {
                const char* xp = sXH + lrow * 528 + (kbase + lgrp * 8) * 2;
                ah = *(const bf16x8*)xp;
                al = *(const bf16x8*)(xp + 8448);
            } else {
                const int off = (kbase + lgrp * 8 - 256) * 2;
                ah = *(const bf16x8*)(phr + off);
                al = *(const bf16x8*)(plr + off);
            }
            acc = __builtin_amdgcn_mfma_f32_16x16x32_bf16(ah, wfhi[j], acc, 0, 0, 0);
            acc = __builtin_amdgcn_mfma_f32_16x16x32_bf16(ah, wflo[j], acc, 0, 0, 0);
            acc = __builtin_amdgcn_mfma_f32_16x16x32_bf16(al, wfhi[j], acc, 0, 0, 0);
        }
        // m-tile MFMA (owners): m_t = m_{t-1}@(I+AT) + u*BT
        f32x4 acc2 = {0.f, 0.f, 0.f, 0.f};
        if (mwg) {
            #pragma unroll
            for (int j2 = 0; j2 < 2; ++j2) {
                const int off = (1024 + wave * 64 + j2 * 32 + lgrp * 8) * 2;
                bf16x8 ah = *(const bf16x8*)(phr + off);
                bf16x8 al = *(const bf16x8*)(plr + off);
                acc2 = __builtin_amdgcn_mfma_f32_16x16x32_bf16(ah, m1hi[j2], acc2, 0, 0, 0);
                acc2 = __builtin_amdgcn_mfma_f32_16x16x32_bf16(ah, m1lo[j2], acc2, 0, 0, 0);
                acc2 = __builtin_amdgcn_mfma_f32_16x16x32_bf16(al, m1hi[j2], acc2, 0, 0, 0);
            }
        }
        if (wave != 0) {
            ((f32x4*)(smem + RED_OFF))[(wave - 1) * 64 + lane] = acc;
            if (mwg) ((f32x4*)(smem + RED2_OFF))[(wave - 1) * 64 + lane] = acc2;
        }
        __syncthreads();

        // epilogue (wave0): h_t, out store, plane stores, next-step u partials
        if (wave == 0) {
            f32x4 a0 = acc;
            #pragma unroll
            for (int w = 0; w < 3; ++w) a0 += ((const f32x4*)(smem + RED_OFF))[w * 64 + lane];
            f32x4 a2 = acc2;
            if (mwg) {
                #pragma unroll
                for (int w = 0; w < 3; ++w) a2 += ((const f32x4*)(smem + RED2_OFF))[w * 64 + lane];
            }
            char* PHn = PB + (size_t)((t + 1) & 1) * PSET;
            char* PLn = PHn + PLO;
            float* UPn = UPf + (size_t)((t + 1) & 1) * 64 * 80;
            #pragma unroll
            for (int r = 0; r < 4; ++r) {
                const int brow = lgrp * 4 + r;
                const int b = b0 + brow;
                const float uu = ULDS[brow];
                const float hval = tanhf(a0[r] + uu * bvreg);
                out[((size_t)b * SEQ + t) * UNITS + n0 + lrow] = hval;
                unsigned short hh = bf16rn(hval);
                unsigned short hl = bf16rn(hval - bf2f(hh));
                *(unsigned short*)(PHn + (size_t)b * PROWB + 2 * (n0 + lrow)) = hh;
                *(unsigned short*)(PLn + (size_t)b * PROWB + 2 * (n0 + lrow)) = hl;
                float ps = hval * hereg;
                ps += __shfl_xor(ps, 1, 64);
                ps += __shfl_xor(ps, 2, 64);
                ps += __shfl_xor(ps, 4, 64);
                ps += __shfl_xor(ps, 8, 64);
                if (lrow == 0) UPn[(size_t)b * 80 + lid] = ps;
                if (mwg) {
                    const float mval = a2[r] + uu * btreg;
                    unsigned short mh = bf16rn(mval);
                    unsigned short ml = bf16rn(mval - bf2f(mh));
                    const size_t mo = (size_t)b * PROWB + 2 * (1024 + mt * 16 + lrow);
                    *(unsigned short*)(PHn + mo) = mh;
                    *(unsigned short*)(PLn + mo) = ml;
                    float pm = mval * mereg;
                    pm += __shfl_xor(pm, 1, 64);
                    pm += __shfl_xor(pm, 2, 64);
                    pm += __shfl_xor(pm, 4, 64);
                    pm += __shfl_xor(pm, 8, 64);
                    if (lrow == 0) UPn[(size_t)b * 80 + 64 + mt] = pm;
                }
            }
        }
    }
}

extern "C" void kernel_launch(void* const* d_in, const int* in_sizes, int n_in,
                              void* d_out, int out_size, void* d_ws, size_t ws_size,
                              hipStream_t stream) {
    const float* x  = (const float*)d_in[0];
    const float* ie = (const float*)d_in[1];
    const float* he = (const float*)d_in[2];
    const float* me = (const float*)d_in[3];
    const float* Wi = (const float*)d_in[4];
    const float* Wh = (const float*)d_in[5];
    const float* Wm = (const float*)d_in[6];
    const float* AT = (const float*)d_in[7];
    const float* BT = (const float*)d_in[8];
    float* out = (float*)d_out;
    char* ws   = (char*)d_ws;
    (void)in_sizes; (void)n_in; (void)out_size; (void)ws_size;

    hipLaunchKernelGGL(lmu_pre, dim3((BATCH * SEQ * 64) / 256), dim3(256), 0, stream,
                       x, ie, ws);

    // Regular (non-cooperative) launch: 256 blocks always co-resident (see gbar note).
    hipLaunchKernelGGL(lmu_main, dim3(256), dim3(256), LDS_BYTES, stream,
                       x, he, me, Wi, Wh, Wm, AT, BT, out, ws);
}

// Round 10
// 6066.059 us; speedup vs baseline: 9.3745x; 1.4679x over previous
//
#include <hip/hip_runtime.h>
#include <cmath>

static constexpr int UNITS = 1024;
static constexpr int ORDER = 256;
static constexpr int D_IN  = 256;
static constexpr int BATCH = 64;
static constexpr int SEQ   = 512;
static constexpr int PROWU = 1280;           // plane row: 1280 packed u32  [h(1024)|m(256)]
static constexpr int PROWB = PROWU * 4;      // 5120 B

// ws byte layout
static constexpr size_t XE_OFF = 0;          // 64*512 f32 = 131072
static constexpr size_t FG_OFF = 131072;     // 4 groups * 256 u32 = 4096
static constexpr size_t UP_OFF = 135168;     // 2 slots * 64 b * 80 f32 = 40960
static constexpr size_t P_OFF  = 176128;     // 2 sets * PSET
static constexpr size_t PSET   = 327680;     // 64 rows * 5120 B
// zero region [FG_OFF, P_OFF+2*PSET) = 700416 B = 175104 words

// dynamic-LDS byte offsets
static constexpr int SXH_OFF  = 0;           // x hi plane [16][528B]
static constexpr int SXL_OFF  = 8448;        // x lo plane [16][528B]
static constexpr int RED_OFF  = 16896;       // 1024 f32: slot r*256 + wave*64 + lane
static constexpr int RED2_OFF = 20992;       // 1024 f32
static constexpr int ULDS_OFF = 25088;       // 16 f32
static constexpr int BVS_OFF  = 25152;       // 16 f32
static constexpr int LDS_BYTES = 25216;
// setup-only alias: WMC = [256][16] f32 = 16384 B at offset 0 (< SXH live window)

typedef __attribute__((ext_vector_type(8))) short bf16x8;
typedef __attribute__((ext_vector_type(4))) float f32x4;
typedef unsigned long long u64;

__device__ __forceinline__ unsigned short bf16rn(float f) {
    unsigned u = __builtin_bit_cast(unsigned, f);
    u += 0x7FFFu + ((u >> 16) & 1u);
    return (unsigned short)(u >> 16);
}
__device__ __forceinline__ float bf2f(unsigned short h) {
    unsigned u = ((unsigned)h) << 16;
    return __builtin_bit_cast(float, u);
}

// ---- L2-bypass data path: relaxed system-scope atomics (compiler-managed).
// Lower to global_load_dwordx2 / global_store_dword with sc0 sc1 (coherence
// point = memory-side Infinity Cache), NO fence/cache-maintenance instructions.
__device__ __forceinline__ u64 ld_sys(const void* p) {
    return __hip_atomic_load((const u64*)p, __ATOMIC_RELAXED, __HIP_MEMORY_SCOPE_SYSTEM);
}
__device__ __forceinline__ void st_sys32(void* p, unsigned v) {
    __hip_atomic_store((unsigned*)p, v, __ATOMIC_RELAXED, __HIP_MEMORY_SCOPE_SYSTEM);
}

// 64-wg group barrier, no cache maintenance. Entry __syncthreads drains each
// wave's vmem (compiler emits vmcnt(0) before s_barrier), so all this wg's
// sc0sc1 stores are at L3 before the flag releases; flag store embeds its own
// drain as belt-and-braces. Poll is a tiny self-contained asm (dead output).
// Co-residency: 256 blocks, 25KB LDS, 4 waves -> >=1 block/CU on 256 CUs.
__device__ __forceinline__ void gbar(unsigned* gf, int lid, unsigned gen) {
    __syncthreads();
    if (threadIdx.x == 0) {
        asm volatile("s_waitcnt vmcnt(0)\n\t"
                     "global_store_dword %0, %1, off sc0 sc1"
                     :: "v"(gf + lid), "v"(gen) : "memory");
    }
    if (threadIdx.x < 64) {
        const unsigned* fp = gf + threadIdx.x;
        unsigned v;
        for (;;) {
            asm volatile("global_load_dword %0, %1, off sc0 sc1\n\t"
                         "s_waitcnt vmcnt(0)"
                         : "=v"(v) : "v"(fp) : "memory");
            if (v >= gen) break;
            __builtin_amdgcn_s_sleep(1);
        }
    }
    __syncthreads();
    __builtin_amdgcn_sched_barrier(0);
}

// unpack 4 u64 (8 packed u32 elements: hi16|lo16) into hi/lo bf16x8 fragments
__device__ __forceinline__ void unpack8(const u64* w, bf16x8& hi, bf16x8& lo) {
    #pragma unroll
    for (int e = 0; e < 8; ++e) {
        unsigned u = (unsigned)(w[e >> 1] >> ((e & 1) ? 32 : 0));
        hi[e] = (short)(u >> 16);
        lo[e] = (short)(u & 0xFFFFu);
    }
}

__global__ __launch_bounds__(256) void lmu_pre(const float* __restrict__ x,
                                               const float* __restrict__ ie,
                                               char* __restrict__ ws) {
    int gid  = blockIdx.x * blockDim.x + threadIdx.x;
    int wave = gid >> 6;
    int lane = gid & 63;
    if (wave < BATCH * SEQ) {
        const float* row = x + (size_t)wave * D_IN;
        float s = 0.f;
        #pragma unroll
        for (int c = 0; c < D_IN; c += 64) s += row[c + lane] * ie[c + lane];
        #pragma unroll
        for (int off = 32; off > 0; off >>= 1) s += __shfl_down(s, off);
        if (lane == 0) ((float*)(ws + XE_OFF))[wave] = s;
    }
    // zero flags + both UP slots + both plane sets (contiguous region)
    if (gid < 175104) ((unsigned*)(ws + FG_OFF))[gid] = 0u;
}

__global__ __launch_bounds__(256, 1) void lmu_main(
        const float* __restrict__ x,
        const float* __restrict__ he,
        const float* __restrict__ me,
        const float* __restrict__ Wi,
        const float* __restrict__ Wh,
        const float* __restrict__ Wm,
        const float* __restrict__ AT,
        const float* __restrict__ BT,
        float* __restrict__ out,
        char* __restrict__ ws) {
    extern __shared__ char smem[];
    char*  sXH  = smem + SXH_OFF;
    char*  sXL  = smem + SXL_OFF;
    float* REDs = (float*)(smem + RED_OFF);
    float* RED2 = (float*)(smem + RED2_OFF);
    float* ULDS = (float*)(smem + ULDS_OFF);
    float* BVs  = (float*)(smem + BVS_OFF);
    float* WMC  = (float*)smem;              // setup-only alias

    const int wg = blockIdx.x, tid = threadIdx.x;
    const int wave = tid >> 6, lane = tid & 63;
    const int lrow = lane & 15, lgrp = lane >> 4;
    const int grp = wg >> 6, lid = wg & 63;
    const int b0 = grp * 16, n0 = lid * 16, nglob = n0 + lrow;
    const bool mwg = (lid < 16);
    const int mt = lid & 15;

    float* XE  = (float*)(ws + XE_OFF);
    unsigned* gf = (unsigned*)(ws + FG_OFF) + (size_t)grp * 256;
    float* UPf = (float*)(ws + UP_OFF);
    char* PB   = ws + P_OFF;

    // ---------------- setup ----------------
    for (int idx = tid; idx < ORDER * 16; idx += 256)
        WMC[idx] = Wm[(size_t)(idx >> 4) * UNITS + n0 + (idx & 15)];
    __syncthreads();

    // weight fragments: [Wi; Wh; Wm'] with Wm' = (I+AT)@Wm, bf16 hi/lo
    bf16x8 wfhi[12], wflo[12];
    #pragma unroll
    for (int j = 0; j < 12; ++j) {
        const int kbase = wave * 384 + j * 32 + lgrp * 8;
        bf16x8 vh, vl;
        #pragma unroll
        for (int e = 0; e < 8; ++e) {
            const int k = kbase + e;
            float f;
            if (k < 256)       f = Wi[(size_t)k * UNITS + nglob];
            else if (k < 1280) f = Wh[(size_t)(k - 256) * UNITS + nglob];
            else {
                const int r = k - 1280;
                float s = WMC[r * 16 + lrow];
                const float* atr = AT + (size_t)r * ORDER;
                for (int l = 0; l < ORDER; ++l) s += atr[l] * WMC[l * 16 + lrow];
                f = s;
            }
            unsigned short hb = bf16rn(f);
            unsigned short lb = bf16rn(f - bf2f(hb));
            vh[e] = (short)hb; vl[e] = (short)lb;
        }
        wfhi[j] = vh; wflo[j] = vl;
    }
    // bv[n] = sum_l BT[l] * Wm[l][n]
    {
        const int nl = tid & 15, seg = tid >> 4;
        float s = 0.f;
        for (int l = seg * 16; l < seg * 16 + 16; ++l) s += BT[l] * WMC[l * 16 + nl];
        REDs[tid] = s;
    }
    __syncthreads();
    if (tid < 16) {
        float s = 0.f;
        for (int sg = 0; sg < 16; ++sg) s += REDs[sg * 16 + tid];
        BVs[tid] = s;
    }
    // M1 = (I+AT) fragments for owner wgs
    bf16x8 m1hi[2], m1lo[2];
    float btreg = 0.f, mereg = 0.f;
    if (mwg) {
        #pragma unroll
        for (int j2 = 0; j2 < 2; ++j2) {
            const int kb = wave * 64 + j2 * 32 + lgrp * 8;
            const int c = mt * 16 + lrow;
            bf16x8 vh, vl;
            #pragma unroll
            for (int e = 0; e < 8; ++e) {
                const int r = kb + e;
                float f = AT[(size_t)r * ORDER + c] + ((r == c) ? 1.f : 0.f);
                unsigned short hb = bf16rn(f);
                unsigned short lb = bf16rn(f - bf2f(hb));
                vh[e] = (short)hb; vl[e] = (short)lb;
            }
            m1hi[j2] = vh; m1lo[j2] = vl;
        }
        btreg = BT[mt * 16 + lrow];
        mereg = me[mt * 16 + lrow];
    }
    __syncthreads();
    const float bvreg = BVs[lrow];
    const float hereg = he[n0 + lrow];

    // ---------------- time loop: ONE group barrier per step ----------------
    for (int t = 0; t < SEQ; ++t) {
        // stage x_t (wg-local, pre-barrier): fp32 -> bf16 hi/lo into sX
        {
            const int row = tid >> 4, cs = tid & 15;
            const float4* xr = (const float4*)(x + ((size_t)(b0 + row) * SEQ + t) * D_IN
                                               + cs * 16);
            float4 v0 = xr[0], v1 = xr[1], v2 = xr[2], v3 = xr[3];
            float fs[16] = {v0.x,v0.y,v0.z,v0.w, v1.x,v1.y,v1.z,v1.w,
                            v2.x,v2.y,v2.z,v2.w, v3.x,v3.y,v3.z,v3.w};
            unsigned* dh = (unsigned*)(sXH + row * 528 + cs * 32);
            unsigned* dl = (unsigned*)(sXL + row * 528 + cs * 32);
            #pragma unroll
            for (int q = 0; q < 8; ++q) {
                unsigned short h0 = bf16rn(fs[2*q]),   h1 = bf16rn(fs[2*q+1]);
                unsigned short l0 = bf16rn(fs[2*q]   - bf2f(h0));
                unsigned short l1 = bf16rn(fs[2*q+1] - bf2f(h1));
                dh[q] = (unsigned)h0 | ((unsigned)h1 << 16);
                dl[q] = (unsigned)l0 | ((unsigned)l1 << 16);
            }
        }

        gbar(gf, lid, (unsigned)(t + 1));

        const char* PC = PB + (size_t)(t & 1) * PSET + (size_t)(b0 + lrow) * PROWB;

        // ---- L3 loads (compiler-managed relaxed system atomics) ----
        u64 gh[12][4], gm2[2][4], upv[10];
        if (wave == 0) {
            const int bl = lane >> 2, q = lane & 3;
            const char* pp = (const char*)(UPf + ((size_t)(t & 1) * 64 + b0 + bl) * 80
                                           + q * 20);
            #pragma unroll
            for (int i = 0; i < 10; ++i) upv[i] = ld_sys(pp + i * 8);
            #pragma unroll
            for (int j = 8; j < 12; ++j) {
                const int ei = j * 32 + lgrp * 8 - 256;
                #pragma unroll
                for (int q2 = 0; q2 < 4; ++q2)
                    gh[j][q2] = ld_sys(PC + (size_t)ei * 4 + q2 * 8);
            }
        } else {
            #pragma unroll
            for (int j = 0; j < 12; ++j) {
                const int ei = wave * 384 + j * 32 + lgrp * 8 - 256;
                #pragma unroll
                for (int q2 = 0; q2 < 4; ++q2)
                    gh[j][q2] = ld_sys(PC + (size_t)ei * 4 + q2 * 8);
            }
        }
        if (mwg) {
            #pragma unroll
            for (int j2 = 0; j2 < 2; ++j2) {
                const int ei = 1024 + wave * 64 + j2 * 32 + lgrp * 8;
                #pragma unroll
                for (int q2 = 0; q2 < 4; ++q2)
                    gm2[j2][q2] = ld_sys(PC + (size_t)ei * 4 + q2 * 8);
            }
        }

        // u[b] = XE + sum of 80 partials (wave0)
        if (wave == 0) {
            const int bl = lane >> 2, q = lane & 3;
            float s = 0.f;
            #pragma unroll
            for (int i = 0; i < 10; ++i) {
                s += __builtin_bit_cast(float, (unsigned)(upv[i] & 0xFFFFFFFFu))
                   + __builtin_bit_cast(float, (unsigned)(upv[i] >> 32));
            }
            s += __shfl_xor(s, 1, 64);
            s += __shfl_xor(s, 2, 64);
            if (q == 0) ULDS[bl] = XE[(size_t)(b0 + bl) * SEQ + t] + s;
        }

        // h-tile MFMA (3-term bf16 split)
        f32x4 acc = {0.f, 0.f, 0.f, 0.f};
        if (wave == 0) {
            #pragma unroll
            for (int j = 0; j < 8; ++j) {
                const char* xp = sXH + lrow * 528 + (j * 32 + lgrp * 8) * 2;
                bf16x8 ah = *(const bf16x8*)xp;
                bf16x8 al = *(const bf16x8*)(xp + 8448);
                acc = __builtin_amdgcn_mfma_f32_16x16x32_bf16(ah, wfhi[j], acc, 0, 0, 0);
                acc = __builtin_amdgcn_mfma_f32_16x16x32_bf16(ah, wflo[j], acc, 0, 0, 0);
                acc = __builtin_amdgcn_mfma_f32_16x16x32_bf16(al, wfhi[j], acc, 0, 0, 0);
            }
            #pragma unroll
            for (int j = 8; j < 12; ++j) {
                bf16x8 ah, al;
                unpack8(gh[j], ah, al);
                acc = __builtin_amdgcn_mfma_f32_16x16x32_bf16(ah, wfhi[j], acc, 0, 0, 0);
                acc = __builtin_amdgcn_mfma_f32_16x16x32_bf16(ah, wflo[j], acc, 0, 0, 0);
                acc = __builtin_amdgcn_mfma_f32_16x16x32_bf16(al, wfhi[j], acc, 0, 0, 0);
            }
        } else {
            #pragma unroll
            for (int j = 0; j < 12; ++j) {
                bf16x8 ah, al;
                unpack8(gh[j], ah, al);
                acc = __builtin_amdgcn_mfma_f32_16x16x32_bf16(ah, wfhi[j], acc, 0, 0, 0);
                acc = __builtin_amdgcn_mfma_f32_16x16x32_bf16(ah, wflo[j], acc, 0, 0, 0);
                acc = __builtin_amdgcn_mfma_f32_16x16x32_bf16(al, wfhi[j], acc, 0, 0, 0);
            }
        }
        // m-tile MFMA (owners)
        f32x4 acc2 = {0.f, 0.f, 0.f, 0.f};
        if (mwg) {
            #pragma unroll
            for (int j2 = 0; j2 < 2; ++j2) {
                bf16x8 ah, al;
                unpack8(gm2[j2], ah, al);
                acc2 = __builtin_amdgcn_mfma_f32_16x16x32_bf16(ah, m1hi[j2], acc2, 0, 0, 0);
                acc2 = __builtin_amdgcn_mfma_f32_16x16x32_bf16(ah, m1lo[j2], acc2, 0, 0, 0);
                acc2 = __builtin_amdgcn_mfma_f32_16x16x32_bf16(al, m1hi[j2], acc2, 0, 0, 0);
            }
        }

        // cross-wave K-reduction exchange (conflict-free scalar layout)
        #pragma unroll
        for (int r = 0; r < 4; ++r) {
            REDs[r * 256 + wave * 64 + lane] = acc[r];
            if (mwg) RED2[r * 256 + wave * 64 + lane] = acc2[r];
        }
        __syncthreads();

        // distributed epilogue: wave w handles accumulator slot r = w
        {
            const int w = wave;
            const int brow = lgrp * 4 + w;
            const int b = b0 + brow;
            float a0 = REDs[w * 256 + 0 * 64 + lane] + REDs[w * 256 + 1 * 64 + lane]
                     + REDs[w * 256 + 2 * 64 + lane] + REDs[w * 256 + 3 * 64 + lane];
            const float uu = ULDS[brow];
            const float hval = tanhf(a0 + uu * bvreg);
            out[((size_t)b * SEQ + t) * UNITS + n0 + lrow] = hval;
            unsigned short hh = bf16rn(hval);
            unsigned short hl = bf16rn(hval - bf2f(hh));
            char* PN = PB + (size_t)((t + 1) & 1) * PSET + (size_t)b * PROWB;
            st_sys32(PN + (size_t)(n0 + lrow) * 4, ((unsigned)hh << 16) | hl);
            float ps = hval * hereg;
            ps += __shfl_xor(ps, 1, 64);
            ps += __shfl_xor(ps, 2, 64);
            ps += __shfl_xor(ps, 4, 64);
            ps += __shfl_xor(ps, 8, 64);
            float* UPn = UPf + (size_t)(((t + 1) & 1) * 64) * 80;
            if (lrow == 0)
                st_sys32(&UPn[(size_t)b * 80 + lid], __builtin_bit_cast(unsigned, ps));
            if (mwg) {
                float a2 = RED2[w * 256 + 0 * 64 + lane] + RED2[w * 256 + 1 * 64 + lane]
                         + RED2[w * 256 + 2 * 64 + lane] + RED2[w * 256 + 3 * 64 + lane];
                const float mval = a2 + uu * btreg;
                unsigned short mh = bf16rn(mval);
                unsigned short ml = bf16rn(mval - bf2f(mh));
                st_sys32(PN + (size_t)(1024 + mt * 16 + lrow) * 4,
                         ((unsigned)mh << 16) | ml);
                float pm = mval * mereg;
                pm += __shfl_xor(pm, 1, 64);
                pm += __shfl_xor(pm, 2, 64);
                pm += __shfl_xor(pm, 4, 64);
                pm += __shfl_xor(pm, 8, 64);
                if (lrow == 0)
                    st_sys32(&UPn[(size_t)b * 80 + 64 + mt],
                             __builtin_bit_cast(unsigned, pm));
            }
        }
    }
}

extern "C" void kernel_launch(void* const* d_in, const int* in_sizes, int n_in,
                              void* d_out, int out_size, void* d_ws, size_t ws_size,
                              hipStream_t stream) {
    const float* x  = (const float*)d_in[0];
    const float* ie = (const float*)d_in[1];
    const float* he = (const float*)d_in[2];
    const float* me = (const float*)d_in[3];
    const float* Wi = (const float*)d_in[4];
    const float* Wh = (const float*)d_in[5];
    const float* Wm = (const float*)d_in[6];
    const float* AT = (const float*)d_in[7];
    const float* BT = (const float*)d_in[8];
    float* out = (float*)d_out;
    char* ws   = (char*)d_ws;
    (void)in_sizes; (void)n_in; (void)out_size; (void)ws_size;

    hipLaunchKernelGGL(lmu_pre, dim3((BATCH * SEQ * 64) / 256), dim3(256), 0, stream,
                       x, ie, ws);

    hipLaunchKernelGGL(lmu_main, dim3(256), dim3(256), LDS_BYTES, stream,
                       x, he, me, Wi, Wh, Wm, AT, BT, out, ws);
}

// Round 11
// 3204.365 us; speedup vs baseline: 17.7465x; 1.8931x over previous
//
#include <hip/hip_runtime.h>
#include <cmath>

static constexpr int UNITS = 1024;
static constexpr int ORDER = 256;
static constexpr int D_IN  = 256;
static constexpr int BATCH = 64;
static constexpr int SEQ   = 512;
static constexpr int PROWB = 2560;           // bytes per plane row: (1024 h + 256 m) bf16

// ws byte layout (identical footprint to R10)
static constexpr size_t XE_OFF = 0;          // 64*512 f32
static constexpr size_t FG_OFF = 131072;     // 4 groups * 256 u32
static constexpr size_t UP_OFF = 135168;     // 2 slots * 64 b * 80 f32
static constexpr size_t P_OFF  = 176128;     // 2 sets * PSET
static constexpr size_t PSET   = 327680;     // hi plane 64*2560 + lo plane 64*2560
static constexpr size_t PLO    = 163840;     // lo-plane offset within a set
// zero region [FG_OFF, P_OFF+2*PSET) = 700416 B = 175104 words

// dynamic-LDS byte offsets (base 16B-aligned)
static constexpr int SXH_OFF  = 0;           // x hi plane [16][528B]
static constexpr int SXL_OFF  = 8448;        // x lo plane [16][528B]
static constexpr int ACTH_OFF = 16896;       // act hi [16][ACTROW]
static constexpr int ACTROW   = 2576;        // 2560 + 16 pad (16B multiple)
static constexpr int ACTL_OFF = 16896 + 16 * 2576;          // 58112
static constexpr int RED_OFF  = 58112 + 16 * 2576;          // 99328  (1024 f32)
static constexpr int RED2_OFF = 99328 + 4096;               // 103424 (1024 f32)
static constexpr int ULDS_OFF = 107520;      // 16 f32
static constexpr int BVS_OFF  = 107584;      // 16 f32
static constexpr int LDS_BYTES = 107648;
// setup-only alias: WMC = [256][16] f32 = 16384 B at offset 0

typedef __attribute__((ext_vector_type(8))) short bf16x8;
typedef __attribute__((ext_vector_type(4))) float f32x4;
typedef unsigned long long u64;

__device__ __forceinline__ unsigned short bf16rn(float f) {
    unsigned u = __builtin_bit_cast(unsigned, f);
    u += 0x7FFFu + ((u >> 16) & 1u);
    return (unsigned short)(u >> 16);
}
__device__ __forceinline__ float bf2f(unsigned short h) {
    unsigned u = ((unsigned)h) << 16;
    return __builtin_bit_cast(float, u);
}

// ---- L2-bypass data path: relaxed system-scope atomics (compiler-managed,
// lower to sc0 sc1 global ops, coherence point = Infinity Cache, no fences).
__device__ __forceinline__ u64 ld_sys(const void* p) {
    return __hip_atomic_load((const u64*)p, __ATOMIC_RELAXED, __HIP_MEMORY_SCOPE_SYSTEM);
}
__device__ __forceinline__ void st_sys32(void* p, unsigned v) {
    __hip_atomic_store((unsigned*)p, v, __ATOMIC_RELAXED, __HIP_MEMORY_SCOPE_SYSTEM);
}

__global__ __launch_bounds__(256) void lmu_pre(const float* __restrict__ x,
                                               const float* __restrict__ ie,
                                               char* __restrict__ ws) {
    int gid  = blockIdx.x * blockDim.x + threadIdx.x;
    int wave = gid >> 6;
    int lane = gid & 63;
    if (wave < BATCH * SEQ) {
        const float* row = x + (size_t)wave * D_IN;
        float s = 0.f;
        #pragma unroll
        for (int c = 0; c < D_IN; c += 64) s += row[c + lane] * ie[c + lane];
        #pragma unroll
        for (int off = 32; off > 0; off >>= 1) s += __shfl_down(s, off);
        if (lane == 0) ((float*)(ws + XE_OFF))[wave] = s;
    }
    // zero flags + both UP slots + both plane sets (contiguous region)
    if (gid < 175104) ((unsigned*)(ws + FG_OFF))[gid] = 0u;
}

__global__ __launch_bounds__(256, 1) void lmu_main(
        const float* __restrict__ x,
        const float* __restrict__ he,
        const float* __restrict__ me,
        const float* __restrict__ Wi,
        const float* __restrict__ Wh,
        const float* __restrict__ Wm,
        const float* __restrict__ AT,
        const float* __restrict__ BT,
        float* __restrict__ out,
        char* __restrict__ ws) {
    extern __shared__ char smem[];
    char*  sXH  = smem + SXH_OFF;
    char*  sXL  = smem + SXL_OFF;
    float* REDs = (float*)(smem + RED_OFF);
    float* RED2 = (float*)(smem + RED2_OFF);
    float* ULDS = (float*)(smem + ULDS_OFF);
    float* BVs  = (float*)(smem + BVS_OFF);
    float* WMC  = (float*)smem;              // setup-only alias

    const int wg = blockIdx.x, tid = threadIdx.x;
    const int wave = tid >> 6, lane = tid & 63;
    const int lrow = lane & 15, lgrp = lane >> 4;
    const int grp = wg >> 6, lid = wg & 63;
    const int b0 = grp * 16, n0 = lid * 16, nglob = n0 + lrow;
    const bool mwg = (lid < 16);
    const int mt = lid & 15;

    float* XE  = (float*)(ws + XE_OFF);
    unsigned* gf = (unsigned*)(ws + FG_OFF) + (size_t)grp * 256;
    float* UPf = (float*)(ws + UP_OFF);
    char* PB   = ws + P_OFF;

    // ---------------- setup ----------------
    for (int idx = tid; idx < ORDER * 16; idx += 256)
        WMC[idx] = Wm[(size_t)(idx >> 4) * UNITS + n0 + (idx & 15)];
    __syncthreads();

    // weight fragments: [Wi; Wh; Wm'] with Wm' = (I+AT)@Wm, bf16 hi/lo
    bf16x8 wfhi[12], wflo[12];
    #pragma unroll
    for (int j = 0; j < 12; ++j) {
        const int kbase = wave * 384 + j * 32 + lgrp * 8;
        bf16x8 vh, vl;
        #pragma unroll
        for (int e = 0; e < 8; ++e) {
            const int k = kbase + e;
            float f;
            if (k < 256)       f = Wi[(size_t)k * UNITS + nglob];
            else if (k < 1280) f = Wh[(size_t)(k - 256) * UNITS + nglob];
            else {
                const int r = k - 1280;
                float s = WMC[r * 16 + lrow];
                const float* atr = AT + (size_t)r * ORDER;
                for (int l = 0; l < ORDER; ++l) s += atr[l] * WMC[l * 16 + lrow];
                f = s;
            }
            unsigned short hb = bf16rn(f);
            unsigned short lb = bf16rn(f - bf2f(hb));
            vh[e] = (short)hb; vl[e] = (short)lb;
        }
        wfhi[j] = vh; wflo[j] = vl;
    }
    // bv[n] = sum_l BT[l] * Wm[l][n]
    {
        const int nl = tid & 15, seg = tid >> 4;
        float s = 0.f;
        for (int l = seg * 16; l < seg * 16 + 16; ++l) s += BT[l] * WMC[l * 16 + nl];
        REDs[tid] = s;
    }
    __syncthreads();
    if (tid < 16) {
        float s = 0.f;
        for (int sg = 0; sg < 16; ++sg) s += REDs[sg * 16 + tid];
        BVs[tid] = s;
    }
    // M1 = (I+AT) fragments for owner wgs
    bf16x8 m1hi[2], m1lo[2];
    float btreg = 0.f, mereg = 0.f;
    if (mwg) {
        #pragma unroll
        for (int j2 = 0; j2 < 2; ++j2) {
            const int kb = wave * 64 + j2 * 32 + lgrp * 8;
            const int c = mt * 16 + lrow;
            bf16x8 vh, vl;
            #pragma unroll
            for (int e = 0; e < 8; ++e) {
                const int r = kb + e;
                float f = AT[(size_t)r * ORDER + c] + ((r == c) ? 1.f : 0.f);
                unsigned short hb = bf16rn(f);
                unsigned short lb = bf16rn(f - bf2f(hb));
                vh[e] = (short)hb; vl[e] = (short)lb;
            }
            m1hi[j2] = vh; m1lo[j2] = vl;
        }
        btreg = BT[mt * 16 + lrow];
        mereg = me[mt * 16 + lrow];
    }
    __syncthreads();
    const float bvreg = BVs[lrow];
    const float hereg = he[n0 + lrow];

    // ---------------- time loop: ONE group barrier per step ----------------
    for (int t = 0; t < SEQ; ++t) {
        // ---- arrive: drain epilogue stores (syncthreads emits vmcnt(0)), release flag
        __syncthreads();
        if (tid == 0) {
            asm volatile("s_waitcnt vmcnt(0)\n\t"
                         "global_store_dword %0, %1, off sc0 sc1"
                         :: "v"(gf + lid), "v"((unsigned)(t + 1)) : "memory");
        }

        // ---- stage x_t into sX (overlaps other wgs' arrival)
        {
            const int row = tid >> 4, cs = tid & 15;
            const float4* xr = (const float4*)(x + ((size_t)(b0 + row) * SEQ + t) * D_IN
                                               + cs * 16);
            float4 v0 = xr[0], v1 = xr[1], v2 = xr[2], v3 = xr[3];
            float fs[16] = {v0.x,v0.y,v0.z,v0.w, v1.x,v1.y,v1.z,v1.w,
                            v2.x,v2.y,v2.z,v2.w, v3.x,v3.y,v3.z,v3.w};
            unsigned* dh = (unsigned*)(sXH + row * 528 + cs * 32);
            unsigned* dl = (unsigned*)(sXL + row * 528 + cs * 32);
            #pragma unroll
            for (int q = 0; q < 8; ++q) {
                unsigned short h0 = bf16rn(fs[2*q]),   h1 = bf16rn(fs[2*q+1]);
                unsigned short l0 = bf16rn(fs[2*q]   - bf2f(h0));
                unsigned short l1 = bf16rn(fs[2*q+1] - bf2f(h1));
                dh[q] = (unsigned)h0 | ((unsigned)h1 << 16);
                dl[q] = (unsigned)l0 | ((unsigned)l1 << 16);
            }
        }

        // ---- wait: poll all 64 flags
        if (tid < 64) {
            const unsigned* fp = gf + tid;
            unsigned v;
            const unsigned gen = (unsigned)(t + 1);
            for (;;) {
                asm volatile("global_load_dword %0, %1, off sc0 sc1\n\t"
                             "s_waitcnt vmcnt(0)"
                             : "=v"(v) : "v"(fp) : "memory");
                if (v >= gen) break;
                __builtin_amdgcn_s_sleep(1);
            }
        }
        __syncthreads();
        __builtin_amdgcn_sched_barrier(0);

        // ---- bulk load planes -> LDS (contiguous lanes -> full 64B lines at L3)
        const char* PHc = PB + (size_t)(t & 1) * PSET;
        {
            u64 vh[20], vl[20];
            #pragma unroll
            for (int it = 0; it < 20; ++it) {
                const int idx = it * 256 + tid;
                const int row = idx / 320;           // 320 u64 per 2560B row
                const int o8  = idx - row * 320;
                const char* gp = PHc + (size_t)(b0 + row) * PROWB + (size_t)o8 * 8;
                vh[it] = ld_sys(gp);
                vl[it] = ld_sys(gp + PLO);
            }
            #pragma unroll
            for (int it = 0; it < 20; ++it) {
                const int idx = it * 256 + tid;
                const int row = idx / 320;
                const int o8  = idx - row * 320;
                *(u64*)(smem + ACTH_OFF + row * ACTROW + o8 * 8) = vh[it];
                *(u64*)(smem + ACTL_OFF + row * ACTROW + o8 * 8) = vl[it];
            }
        }
        // UP partial loads (wave0) — issued here, consumed after MFMA phase
        u64 upv[10];
        if (wave == 0) {
            const int bl = lane >> 2, q = lane & 3;
            const char* pp = (const char*)(UPf + ((size_t)(t & 1) * 64 + b0 + bl) * 80
                                           + q * 20);
            #pragma unroll
            for (int i = 0; i < 10; ++i) upv[i] = ld_sys(pp + i * 8);
        }
        __syncthreads();   // act LDS ready

        // ---- h-tile MFMA (3-term bf16 split), fragments from LDS
        f32x4 acc = {0.f, 0.f, 0.f, 0.f};
        if (wave == 0) {
            #pragma unroll
            for (int j = 0; j < 8; ++j) {
                const char* xp = sXH + lrow * 528 + (j * 32 + lgrp * 8) * 2;
                bf16x8 ah = *(const bf16x8*)xp;
                bf16x8 al = *(const bf16x8*)(xp + 8448);
                acc = __builtin_amdgcn_mfma_f32_16x16x32_bf16(ah, wfhi[j], acc, 0, 0, 0);
                acc = __builtin_amdgcn_mfma_f32_16x16x32_bf16(ah, wflo[j], acc, 0, 0, 0);
                acc = __builtin_amdgcn_mfma_f32_16x16x32_bf16(al, wfhi[j], acc, 0, 0, 0);
            }
            #pragma unroll
            for (int j = 8; j < 12; ++j) {
                const int elem = j * 32 + lgrp * 8 - 256;
                bf16x8 ah = *(const bf16x8*)(smem + ACTH_OFF + lrow * ACTROW + elem * 2);
                bf16x8 al = *(const bf16x8*)(smem + ACTL_OFF + lrow * ACTROW + elem * 2);
                acc = __builtin_amdgcn_mfma_f32_16x16x32_bf16(ah, wfhi[j], acc, 0, 0, 0);
                acc = __builtin_amdgcn_mfma_f32_16x16x32_bf16(ah, wflo[j], acc, 0, 0, 0);
                acc = __builtin_amdgcn_mfma_f32_16x16x32_bf16(al, wfhi[j], acc, 0, 0, 0);
            }
        } else {
            #pragma unroll
            for (int j = 0; j < 12; ++j) {
                const int elem = wave * 384 + j * 32 + lgrp * 8 - 256;
                bf16x8 ah = *(const bf16x8*)(smem + ACTH_OFF + lrow * ACTROW + elem * 2);
                bf16x8 al = *(const bf16x8*)(smem + ACTL_OFF + lrow * ACTROW + elem * 2);
                acc = __builtin_amdgcn_mfma_f32_16x16x32_bf16(ah, wfhi[j], acc, 0, 0, 0);
                acc = __builtin_amdgcn_mfma_f32_16x16x32_bf16(ah, wflo[j], acc, 0, 0, 0);
                acc = __builtin_amdgcn_mfma_f32_16x16x32_bf16(al, wfhi[j], acc, 0, 0, 0);
            }
        }
        // ---- m-tile MFMA (owners), fragments from LDS
        f32x4 acc2 = {0.f, 0.f, 0.f, 0.f};
        if (mwg) {
            #pragma unroll
            for (int j2 = 0; j2 < 2; ++j2) {
                const int elem = 1024 + wave * 64 + j2 * 32 + lgrp * 8;
                bf16x8 ah = *(const bf16x8*)(smem + ACTH_OFF + lrow * ACTROW + elem * 2);
                bf16x8 al = *(const bf16x8*)(smem + ACTL_OFF + lrow * ACTROW + elem * 2);
                acc2 = __builtin_amdgcn_mfma_f32_16x16x32_bf16(ah, m1hi[j2], acc2, 0, 0, 0);
                acc2 = __builtin_amdgcn_mfma_f32_16x16x32_bf16(ah, m1lo[j2], acc2, 0, 0, 0);
                acc2 = __builtin_amdgcn_mfma_f32_16x16x32_bf16(al, m1hi[j2], acc2, 0, 0, 0);
            }
        }

        // u[b] = XE + sum of 80 partials (wave0, latency hidden under MFMAs)
        if (wave == 0) {
            const int bl = lane >> 2, q = lane & 3;
            float s = 0.f;
            #pragma unroll
            for (int i = 0; i < 10; ++i) {
                s += __builtin_bit_cast(float, (unsigned)(upv[i] & 0xFFFFFFFFu))
                   + __builtin_bit_cast(float, (unsigned)(upv[i] >> 32));
            }
            s += __shfl_xor(s, 1, 64);
            s += __shfl_xor(s, 2, 64);
            if (q == 0) ULDS[bl] = XE[(size_t)(b0 + bl) * SEQ + t] + s;
        }

        // cross-wave K-reduction exchange
        #pragma unroll
        for (int r = 0; r < 4; ++r) {
            REDs[r * 256 + wave * 64 + lane] = acc[r];
            if (mwg) RED2[r * 256 + wave * 64 + lane] = acc2[r];
        }
        __syncthreads();

        // ---- distributed epilogue: wave w handles accumulator slot r = w
        {
            const int w = wave;
            const int brow = lgrp * 4 + w;
            const int b = b0 + brow;
            float a0 = REDs[w * 256 + 0 * 64 + lane] + REDs[w * 256 + 1 * 64 + lane]
                     + REDs[w * 256 + 2 * 64 + lane] + REDs[w * 256 + 3 * 64 + lane];
            const float uu = ULDS[brow];
            const float hval = tanhf(a0 + uu * bvreg);
            out[((size_t)b * SEQ + t) * UNITS + n0 + lrow] = hval;

            char* PNH = PB + (size_t)((t + 1) & 1) * PSET + (size_t)b * PROWB;
            char* PNL = PNH + PLO;
            unsigned hb = bf16rn(hval);
            unsigned lb = bf16rn(hval - bf2f((unsigned short)hb));
            unsigned hbn = __shfl_xor(hb, 1, 64);
            unsigned lbn = __shfl_xor(lb, 1, 64);
            if (!(lrow & 1)) {
                st_sys32(PNH + (size_t)(n0 + lrow) * 2, hb | (hbn << 16));
                st_sys32(PNL + (size_t)(n0 + lrow) * 2, lb | (lbn << 16));
            }
            float ps = hval * hereg;
            ps += __shfl_xor(ps, 1, 64);
            ps += __shfl_xor(ps, 2, 64);
            ps += __shfl_xor(ps, 4, 64);
            ps += __shfl_xor(ps, 8, 64);
            float* UPn = UPf + (size_t)(((t + 1) & 1) * 64) * 80;
            if (lrow == 0)
                st_sys32(&UPn[(size_t)b * 80 + lid], __builtin_bit_cast(unsigned, ps));
            if (mwg) {
                float a2 = RED2[w * 256 + 0 * 64 + lane] + RED2[w * 256 + 1 * 64 + lane]
                         + RED2[w * 256 + 2 * 64 + lane] + RED2[w * 256 + 3 * 64 + lane];
                const float mval = a2 + uu * btreg;
                const int c = mt * 16 + lrow;
                unsigned mh = bf16rn(mval);
                unsigned ml = bf16rn(mval - bf2f((unsigned short)mh));
                unsigned mhn = __shfl_xor(mh, 1, 64);
                unsigned mln = __shfl_xor(ml, 1, 64);
                if (!(lrow & 1)) {
                    st_sys32(PNH + 2048 + (size_t)c * 2, mh | (mhn << 16));
                    st_sys32(PNL + 2048 + (size_t)c * 2, ml | (mln << 16));
                }
                float pm = mval * mereg;
                pm += __shfl_xor(pm, 1, 64);
                pm += __shfl_xor(pm, 2, 64);
                pm += __shfl_xor(pm, 4, 64);
                pm += __shfl_xor(pm, 8, 64);
                if (lrow == 0)
                    st_sys32(&UPn[(size_t)b * 80 + 64 + mt],
                             __builtin_bit_cast(unsigned, pm));
            }
        }
    }
}

extern "C" void kernel_launch(void* const* d_in, const int* in_sizes, int n_in,
                              void* d_out, int out_size, void* d_ws, size_t ws_size,
                              hipStream_t stream) {
    const float* x  = (const float*)d_in[0];
    const float* ie = (const float*)d_in[1];
    const float* he = (const float*)d_in[2];
    const float* me = (const float*)d_in[3];
    const float* Wi = (const float*)d_in[4];
    const float* Wh = (const float*)d_in[5];
    const float* Wm = (const float*)d_in[6];
    const float* AT = (const float*)d_in[7];
    const float* BT = (const float*)d_in[8];
    float* out = (float*)d_out;
    char* ws   = (char*)d_ws;
    (void)in_sizes; (void)n_in; (void)out_size; (void)ws_size;

    hipLaunchKernelGGL(lmu_pre, dim3((BATCH * SEQ * 64) / 256), dim3(256), 0, stream,
                       x, ie, ws);

    hipLaunchKernelGGL(lmu_main, dim3(256), dim3(256), LDS_BYTES, stream,
                       x, he, me, Wi, Wh, Wm, AT, BT, out, ws);
}

// Round 12
// 3069.763 us; speedup vs baseline: 18.5246x; 1.0438x over previous
//
#include <hip/hip_runtime.h>
#include <cmath>

static constexpr int UNITS = 1024;
static constexpr int ORDER = 256;
static constexpr int D_IN  = 256;
static constexpr int BATCH = 64;
static constexpr int SEQ   = 512;

// Swizzled plane: 40 cells x 1024B per plane (k-cells 8..47, k = cell*32 elems
// of [x|h|m] extended vector; cells 0..7 are x, not stored).
// Cell c (c>=8) holds elems k = c*32 + lgrp*8 + e for 16 rows:
//   byte = (c-8)*1024 + (lgrp*16 + row)*16 + e*2
static constexpr int GPLANE = 40960;         // one plane (hi or lo) per group
static constexpr int GSET   = 81920;         // hi+lo per group

// ws byte layout (identical footprint to R11)
static constexpr size_t XE_OFF = 0;          // 64*512 f32
static constexpr size_t FG_OFF = 131072;     // 4 groups * 256 u32
static constexpr size_t UP_OFF = 135168;     // 2 slots * 64 b * 80 f32
static constexpr size_t P_OFF  = 176128;     // 2 sets * PSET
static constexpr size_t PSET   = 327680;     // 4 groups * GSET
// zero region [FG_OFF, P_OFF+2*PSET) = 700416 B = 175104 words

// dynamic-LDS byte offsets (base 16B-aligned)
static constexpr int SXH_OFF  = 0;           // x hi plane [16][528B]
static constexpr int SXL_OFF  = 8448;        // x lo plane [16][528B]
static constexpr int RED_OFF  = 16896;       // 1024 f32: slot r*256 + wave*64 + lane
static constexpr int RED2_OFF = 20992;       // 1024 f32
static constexpr int ULDS_OFF = 25088;       // 16 f32
static constexpr int BVS_OFF  = 25152;       // 16 f32
static constexpr int LDS_BYTES = 25216;
// setup-only alias: WMC = [256][16] f32 = 16384 B at offset 0

typedef __attribute__((ext_vector_type(8))) short bf16x8;
typedef __attribute__((ext_vector_type(4))) float f32x4;
typedef unsigned long long u64;

__device__ __forceinline__ unsigned short bf16rn(float f) {
    unsigned u = __builtin_bit_cast(unsigned, f);
    u += 0x7FFFu + ((u >> 16) & 1u);
    return (unsigned short)(u >> 16);
}
__device__ __forceinline__ float bf2f(unsigned short h) {
    unsigned u = ((unsigned)h) << 16;
    return __builtin_bit_cast(float, u);
}

// ---- L2-bypass data path: relaxed system-scope atomics (compiler-managed,
// lower to sc0 sc1 global ops, coherence point = Infinity Cache, no fences).
__device__ __forceinline__ u64 ld_sys(const void* p) {
    return __hip_atomic_load((const u64*)p, __ATOMIC_RELAXED, __HIP_MEMORY_SCOPE_SYSTEM);
}
__device__ __forceinline__ void st_sys32(void* p, unsigned v) {
    __hip_atomic_store((unsigned*)p, v, __ATOMIC_RELAXED, __HIP_MEMORY_SCOPE_SYSTEM);
}
__device__ __forceinline__ bf16x8 mk8(u64 a, u64 b) {
    union { u64 q[2]; bf16x8 v; } u;
    u.q[0] = a; u.q[1] = b;
    return u.v;
}

__global__ __launch_bounds__(256) void lmu_pre(const float* __restrict__ x,
                                               const float* __restrict__ ie,
                                               char* __restrict__ ws) {
    int gid  = blockIdx.x * blockDim.x + threadIdx.x;
    int wave = gid >> 6;
    int lane = gid & 63;
    if (wave < BATCH * SEQ) {
        const float* row = x + (size_t)wave * D_IN;
        float s = 0.f;
        #pragma unroll
        for (int c = 0; c < D_IN; c += 64) s += row[c + lane] * ie[c + lane];
        #pragma unroll
        for (int off = 32; off > 0; off >>= 1) s += __shfl_down(s, off);
        if (lane == 0) ((float*)(ws + XE_OFF))[wave] = s;
    }
    // zero flags + both UP slots + both plane sets (contiguous region)
    if (gid < 175104) ((unsigned*)(ws + FG_OFF))[gid] = 0u;
}

__global__ __launch_bounds__(256, 1) void lmu_main(
        const float* __restrict__ x,
        const float* __restrict__ he,
        const float* __restrict__ me,
        const float* __restrict__ Wi,
        const float* __restrict__ Wh,
        const float* __restrict__ Wm,
        const float* __restrict__ AT,
        const float* __restrict__ BT,
        float* __restrict__ out,
        char* __restrict__ ws) {
    extern __shared__ char smem[];
    char*  sXH  = smem + SXH_OFF;
    char*  sXL  = smem + SXL_OFF;
    float* REDs = (float*)(smem + RED_OFF);
    float* RED2 = (float*)(smem + RED2_OFF);
    float* ULDS = (float*)(smem + ULDS_OFF);
    float* BVs  = (float*)(smem + BVS_OFF);
    float* WMC  = (float*)smem;              // setup-only alias

    const int wg = blockIdx.x, tid = threadIdx.x;
    const int wave = tid >> 6, lane = tid & 63;
    const int lrow = lane & 15, lgrp = lane >> 4;
    const int grp = wg >> 6, lid = wg & 63;
    const int b0 = grp * 16, n0 = lid * 16, nglob = n0 + lrow;
    const bool mwg = (lid < 16);
    const int mt = lid & 15;

    float* XE  = (float*)(ws + XE_OFF);
    unsigned* gf = (unsigned*)(ws + FG_OFF) + (size_t)grp * 256;
    float* UPf = (float*)(ws + UP_OFF);
    char* PB   = ws + P_OFF;

    // per-thread fragment-load byte offset within a cell
    const int lb = (lgrp * 16 + lrow) * 16;

    // per-thread constant epilogue store offsets (pair stores, even lrow lanes)
    const int rowME = lgrp * 4 + wave;                 // batch row this thread writes
    const int kH = 256 + n0 + (lrow & ~1);
    const int hswz = (kH / 32 - 8) * 1024 + (((kH % 32) / 8) * 16 + rowME) * 16
                   + (kH % 8) * 2;
    const int kM = 1280 + mt * 16 + (lrow & ~1);
    const int mswz = (kM / 32 - 8) * 1024 + (((kM % 32) / 8) * 16 + rowME) * 16
                   + (kM % 8) * 2;

    // ---------------- setup ----------------
    for (int idx = tid; idx < ORDER * 16; idx += 256)
        WMC[idx] = Wm[(size_t)(idx >> 4) * UNITS + n0 + (idx & 15)];
    __syncthreads();

    // weight fragments: [Wi; Wh; Wm'] with Wm' = (I+AT)@Wm, bf16 hi/lo
    bf16x8 wfhi[12], wflo[12];
    #pragma unroll
    for (int j = 0; j < 12; ++j) {
        const int kbase = wave * 384 + j * 32 + lgrp * 8;
        bf16x8 vh, vl;
        #pragma unroll
        for (int e = 0; e < 8; ++e) {
            const int k = kbase + e;
            float f;
            if (k < 256)       f = Wi[(size_t)k * UNITS + nglob];
            else if (k < 1280) f = Wh[(size_t)(k - 256) * UNITS + nglob];
            else {
                const int r = k - 1280;
                float s = WMC[r * 16 + lrow];
                const float* atr = AT + (size_t)r * ORDER;
                for (int l = 0; l < ORDER; ++l) s += atr[l] * WMC[l * 16 + lrow];
                f = s;
            }
            unsigned short hb = bf16rn(f);
            unsigned short lb2 = bf16rn(f - bf2f(hb));
            vh[e] = (short)hb; vl[e] = (short)lb2;
        }
        wfhi[j] = vh; wflo[j] = vl;
    }
    // bv[n] = sum_l BT[l] * Wm[l][n]
    {
        const int nl = tid & 15, seg = tid >> 4;
        float s = 0.f;
        for (int l = seg * 16; l < seg * 16 + 16; ++l) s += BT[l] * WMC[l * 16 + nl];
        REDs[tid] = s;
    }
    __syncthreads();
    if (tid < 16) {
        float s = 0.f;
        for (int sg = 0; sg < 16; ++sg) s += REDs[sg * 16 + tid];
        BVs[tid] = s;
    }
    // M1 = (I+AT) fragments for owner wgs
    bf16x8 m1hi[2], m1lo[2];
    float btreg = 0.f, mereg = 0.f;
    if (mwg) {
        #pragma unroll
        for (int j2 = 0; j2 < 2; ++j2) {
            const int kb = wave * 64 + j2 * 32 + lgrp * 8;
            const int c = mt * 16 + lrow;
            bf16x8 vh, vl;
            #pragma unroll
            for (int e = 0; e < 8; ++e) {
                const int r = kb + e;
                float f = AT[(size_t)r * ORDER + c] + ((r == c) ? 1.f : 0.f);
                unsigned short hb = bf16rn(f);
                unsigned short lb2 = bf16rn(f - bf2f(hb));
                vh[e] = (short)hb; vl[e] = (short)lb2;
            }
            m1hi[j2] = vh; m1lo[j2] = vl;
        }
        btreg = BT[mt * 16 + lrow];
        mereg = me[mt * 16 + lrow];
    }
    __syncthreads();
    const float bvreg = BVs[lrow];
    const float hereg = he[n0 + lrow];

    // ---------------- time loop: ONE group barrier per step ----------------
    for (int t = 0; t < SEQ; ++t) {
        // ---- arrive: syncthreads drains each wave's vmem; flag release
        __syncthreads();
        if (tid == 0) {
            asm volatile("s_waitcnt vmcnt(0)\n\t"
                         "global_store_dword %0, %1, off sc0 sc1"
                         :: "v"(gf + lid), "v"((unsigned)(t + 1)) : "memory");
        }

        // ---- stage x_t into sX (overlaps other wgs' arrival)
        {
            const int row = tid >> 4, cs = tid & 15;
            const float4* xr = (const float4*)(x + ((size_t)(b0 + row) * SEQ + t) * D_IN
                                               + cs * 16);
            float4 v0 = xr[0], v1 = xr[1], v2 = xr[2], v3 = xr[3];
            float fs[16] = {v0.x,v0.y,v0.z,v0.w, v1.x,v1.y,v1.z,v1.w,
                            v2.x,v2.y,v2.z,v2.w, v3.x,v3.y,v3.z,v3.w};
            unsigned* dh = (unsigned*)(sXH + row * 528 + cs * 32);
            unsigned* dl = (unsigned*)(sXL + row * 528 + cs * 32);
            #pragma unroll
            for (int q = 0; q < 8; ++q) {
                unsigned short h0 = bf16rn(fs[2*q]),   h1 = bf16rn(fs[2*q+1]);
                unsigned short l0 = bf16rn(fs[2*q]   - bf2f(h0));
                unsigned short l1 = bf16rn(fs[2*q+1] - bf2f(h1));
                dh[q] = (unsigned)h0 | ((unsigned)h1 << 16);
                dl[q] = (unsigned)l0 | ((unsigned)l1 << 16);
            }
        }

        // ---- wait: poll all 64 flags
        if (tid < 64) {
            const unsigned* fp = gf + tid;
            unsigned v;
            const unsigned gen = (unsigned)(t + 1);
            for (;;) {
                asm volatile("global_load_dword %0, %1, off sc0 sc1\n\t"
                             "s_waitcnt vmcnt(0)"
                             : "=v"(v) : "v"(fp) : "memory");
                if (v >= gen) break;
                __builtin_amdgcn_s_sleep(1);
            }
        }
        __syncthreads();
        __builtin_amdgcn_sched_barrier(0);

        // ---- direct fragment loads from swizzled planes (full-line coalesced)
        const char* GH = PB + (size_t)(t & 1) * PSET + (size_t)grp * GSET;
        const char* GL = GH + GPLANE;

        u64 ah0[12], ah1[12], al0[12], al1[12];
        if (wave == 0) {
            #pragma unroll
            for (int j = 8; j < 12; ++j) {
                const int off = (j - 8) * 1024 + lb;
                ah0[j] = ld_sys(GH + off);     ah1[j] = ld_sys(GH + off + 8);
                al0[j] = ld_sys(GL + off);     al1[j] = ld_sys(GL + off + 8);
            }
        } else {
            #pragma unroll
            for (int j = 0; j < 12; ++j) {
                const int off = (wave * 12 + j - 8) * 1024 + lb;
                ah0[j] = ld_sys(GH + off);     ah1[j] = ld_sys(GH + off + 8);
                al0[j] = ld_sys(GL + off);     al1[j] = ld_sys(GL + off + 8);
            }
        }
        u64 mh0[2], mh1[2], ml0[2], ml1[2];
        if (mwg) {
            #pragma unroll
            for (int j2 = 0; j2 < 2; ++j2) {
                const int off = (32 + 2 * wave + j2) * 1024 + lb;
                mh0[j2] = ld_sys(GH + off);    mh1[j2] = ld_sys(GH + off + 8);
                ml0[j2] = ld_sys(GL + off);    ml1[j2] = ld_sys(GL + off + 8);
            }
        }
        u64 upv[10];
        if (wave == 0) {
            const int bl = lane >> 2, q = lane & 3;
            const char* pp = (const char*)(UPf + ((size_t)(t & 1) * 64 + b0 + bl) * 80
                                           + q * 20);
            #pragma unroll
            for (int i = 0; i < 10; ++i) upv[i] = ld_sys(pp + i * 8);
        }

        // ---- h-tile MFMA (3-term bf16 split)
        f32x4 acc = {0.f, 0.f, 0.f, 0.f};
        if (wave == 0) {
            #pragma unroll
            for (int j = 0; j < 8; ++j) {
                const char* xp = sXH + lrow * 528 + (j * 32 + lgrp * 8) * 2;
                bf16x8 ah = *(const bf16x8*)xp;
                bf16x8 al = *(const bf16x8*)(xp + 8448);
                acc = __builtin_amdgcn_mfma_f32_16x16x32_bf16(ah, wfhi[j], acc, 0, 0, 0);
                acc = __builtin_amdgcn_mfma_f32_16x16x32_bf16(ah, wflo[j], acc, 0, 0, 0);
                acc = __builtin_amdgcn_mfma_f32_16x16x32_bf16(al, wfhi[j], acc, 0, 0, 0);
            }
            #pragma unroll
            for (int j = 8; j < 12; ++j) {
                bf16x8 ah = mk8(ah0[j], ah1[j]);
                bf16x8 al = mk8(al0[j], al1[j]);
                acc = __builtin_amdgcn_mfma_f32_16x16x32_bf16(ah, wfhi[j], acc, 0, 0, 0);
                acc = __builtin_amdgcn_mfma_f32_16x16x32_bf16(ah, wflo[j], acc, 0, 0, 0);
                acc = __builtin_amdgcn_mfma_f32_16x16x32_bf16(al, wfhi[j], acc, 0, 0, 0);
            }
        } else {
            #pragma unroll
            for (int j = 0; j < 12; ++j) {
                bf16x8 ah = mk8(ah0[j], ah1[j]);
                bf16x8 al = mk8(al0[j], al1[j]);
                acc = __builtin_amdgcn_mfma_f32_16x16x32_bf16(ah, wfhi[j], acc, 0, 0, 0);
                acc = __builtin_amdgcn_mfma_f32_16x16x32_bf16(ah, wflo[j], acc, 0, 0, 0);
                acc = __builtin_amdgcn_mfma_f32_16x16x32_bf16(al, wfhi[j], acc, 0, 0, 0);
            }
        }
        // ---- m-tile MFMA (owners)
        f32x4 acc2 = {0.f, 0.f, 0.f, 0.f};
        if (mwg) {
            #pragma unroll
            for (int j2 = 0; j2 < 2; ++j2) {
                bf16x8 ah = mk8(mh0[j2], mh1[j2]);
                bf16x8 al = mk8(ml0[j2], ml1[j2]);
                acc2 = __builtin_amdgcn_mfma_f32_16x16x32_bf16(ah, m1hi[j2], acc2, 0, 0, 0);
                acc2 = __builtin_amdgcn_mfma_f32_16x16x32_bf16(ah, m1lo[j2], acc2, 0, 0, 0);
                acc2 = __builtin_amdgcn_mfma_f32_16x16x32_bf16(al, m1hi[j2], acc2, 0, 0, 0);
            }
        }

        // u[b] = XE + sum of 80 partials (wave0)
        if (wave == 0) {
            const int bl = lane >> 2, q = lane & 3;
            float s = 0.f;
            #pragma unroll
            for (int i = 0; i < 10; ++i) {
                s += __builtin_bit_cast(float, (unsigned)(upv[i] & 0xFFFFFFFFu))
                   + __builtin_bit_cast(float, (unsigned)(upv[i] >> 32));
            }
            s += __shfl_xor(s, 1, 64);
            s += __shfl_xor(s, 2, 64);
            if (q == 0) ULDS[bl] = XE[(size_t)(b0 + bl) * SEQ + t] + s;
        }

        // cross-wave K-reduction exchange
        #pragma unroll
        for (int r = 0; r < 4; ++r) {
            REDs[r * 256 + wave * 64 + lane] = acc[r];
            if (mwg) RED2[r * 256 + wave * 64 + lane] = acc2[r];
        }
        __syncthreads();

        // ---- distributed epilogue: wave w handles accumulator slot r = w
        {
            const int w = wave;
            const int b = b0 + rowME;
            float a0 = REDs[w * 256 + 0 * 64 + lane] + REDs[w * 256 + 1 * 64 + lane]
                     + REDs[w * 256 + 2 * 64 + lane] + REDs[w * 256 + 3 * 64 + lane];
            const float uu = ULDS[rowME];
            const float hval = tanhf(a0 + uu * bvreg);
            out[((size_t)b * SEQ + t) * UNITS + n0 + lrow] = hval;

            char* PNH = PB + (size_t)((t + 1) & 1) * PSET + (size_t)grp * GSET;
            char* PNL = PNH + GPLANE;
            unsigned hb = bf16rn(hval);
            unsigned lb2 = bf16rn(hval - bf2f((unsigned short)hb));
            unsigned hbn = __shfl_xor(hb, 1, 64);
            unsigned lbn = __shfl_xor(lb2, 1, 64);
            if (!(lrow & 1)) {
                st_sys32(PNH + hswz, hb | (hbn << 16));
                st_sys32(PNL + hswz, lb2 | (lbn << 16));
            }
            float ps = hval * hereg;
            ps += __shfl_xor(ps, 1, 64);
            ps += __shfl_xor(ps, 2, 64);
            ps += __shfl_xor(ps, 4, 64);
            ps += __shfl_xor(ps, 8, 64);
            float* UPn = UPf + (size_t)(((t + 1) & 1) * 64) * 80;
            if (lrow == 0)
                st_sys32(&UPn[(size_t)b * 80 + lid], __builtin_bit_cast(unsigned, ps));
            if (mwg) {
                float a2 = RED2[w * 256 + 0 * 64 + lane] + RED2[w * 256 + 1 * 64 + lane]
                         + RED2[w * 256 + 2 * 64 + lane] + RED2[w * 256 + 3 * 64 + lane];
                const float mval = a2 + uu * btreg;
                unsigned mh = bf16rn(mval);
                unsigned ml = bf16rn(mval - bf2f((unsigned short)mh));
                unsigned mhn = __shfl_xor(mh, 1, 64);
                unsigned mln = __shfl_xor(ml, 1, 64);
                if (!(lrow & 1)) {
                    st_sys32(PNH + mswz, mh | (mhn << 16));
                    st_sys32(PNL + mswz, ml | (mln << 16));
                }
                float pm = mval * mereg;
                pm += __shfl_xor(pm, 1, 64);
                pm += __shfl_xor(pm, 2, 64);
                pm += __shfl_xor(pm, 4, 64);
                pm += __shfl_xor(pm, 8, 64);
                if (lrow == 0)
                    st_sys32(&UPn[(size_t)b * 80 + 64 + mt],
                             __builtin_bit_cast(unsigned, pm));
            }
        }
    }
}

extern "C" void kernel_launch(void* const* d_in, const int* in_sizes, int n_in,
                              void* d_out, int out_size, void* d_ws, size_t ws_size,
                              hipStream_t stream) {
    const float* x  = (const float*)d_in[0];
    const float* ie = (const float*)d_in[1];
    const float* he = (const float*)d_in[2];
    const float* me = (const float*)d_in[3];
    const float* Wi = (const float*)d_in[4];
    const float* Wh = (const float*)d_in[5];
    const float* Wm = (const float*)d_in[6];
    const float* AT = (const float*)d_in[7];
    const float* BT = (const float*)d_in[8];
    float* out = (float*)d_out;
    char* ws   = (char*)d_ws;
    (void)in_sizes; (void)n_in; (void)out_size; (void)ws_size;

    hipLaunchKernelGGL(lmu_pre, dim3((BATCH * SEQ * 64) / 256), dim3(256), 0, stream,
                       x, ie, ws);

    hipLaunchKernelGGL(lmu_main, dim3(256), dim3(256), LDS_BYTES, stream,
                       x, he, me, Wi, Wh, Wm, AT, BT, out, ws);
}